// Round 7
// baseline (396.642 us; speedup 1.0000x reference)
//
#include <hip/hip_runtime.h>
#include <math.h>

#define Bc  32
#define Hc  8
#define LQc 256
#define LVc 1024
#define Dc  512

typedef short bf16x8 __attribute__((ext_vector_type(8)));
typedef float f32x4  __attribute__((ext_vector_type(4)));

__device__ __forceinline__ unsigned short f2bf(float x) {   // RNE fp32->bf16
    unsigned u = __builtin_bit_cast(unsigned, x);
    u = (u + 0x7fffu + ((u >> 16) & 1u)) >> 16;
    return (unsigned short)u;
}

__device__ __forceinline__ void gload16(const ushort* g, ushort* l) {
    __builtin_amdgcn_global_load_lds(
        (const __attribute__((address_space(1))) unsigned*)g,
        (__attribute__((address_space(3))) unsigned*)l, 16, 0, 0);
}

// ---------------------------------------------------------------------------
// All 5 weight matrices (each 262144 floats) -> bf16, consecutive dst regions
// ---------------------------------------------------------------------------
__global__ __launch_bounds__(256) void cvt_w(const float* __restrict__ a,
                                             const float* __restrict__ b,
                                             const float* __restrict__ c,
                                             const float* __restrict__ d,
                                             const float* __restrict__ e,
                                             ushort* __restrict__ out) {
    const int i = blockIdx.x * 256 + threadIdx.x;    // [0, 327680)
    const int t = i >> 16, j = i & 65535;
    const float* src = (t == 0) ? a : (t == 1) ? b : (t == 2) ? c : (t == 3) ? d : e;
    float4 v = ((const float4*)src)[j];
    ushort4 o;
    o.x = f2bf(v.x); o.y = f2bf(v.y); o.z = f2bf(v.z); o.w = f2bf(v.w);
    ((ushort4*)(out + (size_t)t * 262144))[j] = o;
}

// ---------------------------------------------------------------------------
// fp32 -> bf16 elementwise convert (vectorized float4 / ushort4)
// ---------------------------------------------------------------------------
__global__ __launch_bounds__(256) void cvt_bf16(const float* __restrict__ in,
                                                ushort* __restrict__ out, int n4) {
    int i = blockIdx.x * 256 + threadIdx.x;
    const int stride = gridDim.x * 256;
    for (; i < n4; i += stride) {
        float4 v = ((const float4*)in)[i];
        ushort4 o;
        o.x = f2bf(v.x); o.y = f2bf(v.y); o.z = f2bf(v.z); o.w = f2bf(v.w);
        ((ushort4*)out)[i] = o;
    }
}

// ---------------------------------------------------------------------------
// fp32 [b][L][D] -> bf16 [b][D][L] transpose+convert, 32x32 LDS tiles
// ---------------------------------------------------------------------------
__global__ __launch_bounds__(256) void transpose_cvt(const float* __restrict__ in,
                                                     ushort* __restrict__ out,
                                                     int L, int D) {
    __shared__ float t[32][33];
    const int b = blockIdx.z;
    const int l0 = blockIdx.x * 32, d0 = blockIdx.y * 32;
    in  += (size_t)b * L * D;
    out += (size_t)b * L * D;
    const int r = threadIdx.x >> 5, c = threadIdx.x & 31;
#pragma unroll
    for (int i = 0; i < 4; i++)
        t[r + 8 * i][c] = in[(size_t)(l0 + r + 8 * i) * D + d0 + c];
    __syncthreads();
#pragma unroll
    for (int i = 0; i < 4; i++)
        out[(size_t)(d0 + r + 8 * i) * L + l0 + c] = f2bf(t[c][r + 8 * i]);
}

// ---------------------------------------------------------------------------
// C[m,n] = alpha * sum_k A[m,k]*B[n,k] (+ bias[m])      (bf16 in, f32 accum)
// 128x128 tile, BK=32, 4 waves (2x2), 4x4 16x16x32 frags per wave.
// CHUNKED conflict-free LDS (group g of 16 rows at g*1024B; chunk c*256B;
// row r*16B; lane l stages row l&15, chunk l>>4 via permuted GLOBAL addr,
// LDS dest linear) + 2-PHASE pipeline (prefetch next K-tile before compute,
// single barrier per iter; end-of-iter __syncthreads drains vmcnt after
// compute so the load latency hides under the MFMAs).
// STORE: 0 = f32 row-major, 1 = bf16 row-major, 2 = bf16 transposed
//        (256-row batches: out[(m>>8)][n][m&255], for v1^T)
// SWIZ:  1 = 1D grid, XCD-grouped decode
// ---------------------------------------------------------------------------
template <int STORE, bool BIAS, int SWIZ>
__global__ __launch_bounds__(256) void gemm_bt(const ushort* __restrict__ A,
                                               const ushort* __restrict__ B,
                                               void* __restrict__ Cv,
                                               const float* __restrict__ bias,
                                               int M, int N, int K, float alpha,
                                               long sA, long sB, long sC,
                                               int byPerXcd) {
    __shared__ __align__(16) ushort As[2][4096];
    __shared__ __align__(16) ushort Bs[2][4096];
    const int z = blockIdx.z;
    A += (size_t)z * sA;
    B += (size_t)z * sB;
    float*  Cf = (float*)Cv  + (size_t)z * sC;
    ushort* Ch = (ushort*)Cv + (size_t)z * sC;

    int bm, bn;
    if constexpr (SWIZ) {
        const int bid = blockIdx.x;
        const int xcd = bid & 7, slot = bid >> 3;
        bm = (xcd * byPerXcd + (slot >> 2)) * 128;
        bn = (slot & 3) * 128;
    } else {
        bm = blockIdx.y * 128;
        bn = blockIdx.x * 128;
    }
    const int tid = threadIdx.x;
    const int wave = tid >> 6, l = tid & 63;
    const int wm = (wave >> 1) * 64, wn = (wave & 1) * 64;
    const int l15 = l & 15, lh = l >> 4;

    f32x4 acc[4][4];
#pragma unroll
    for (int m = 0; m < 4; m++)
#pragma unroll
        for (int n = 0; n < 4; n++) acc[m][n] = (f32x4){0.f, 0.f, 0.f, 0.f};

    // lane-permuted global sources (row = l15 within group, chunk = lh)
    const ushort* gA0 = A + (size_t)(bm + wave * 16 + l15) * K + lh * 8;
    const ushort* gB0 = B + (size_t)(bn + wave * 16 + l15) * K + lh * 8;

    auto STAGE = [&](int bi, int k0) {
        gload16(gA0 + k0,                   As[bi] + wave * 512);
        gload16(gA0 + k0 + (size_t)64 * K,  As[bi] + (wave + 4) * 512);
        gload16(gB0 + k0,                   Bs[bi] + wave * 512);
        gload16(gB0 + k0 + (size_t)64 * K,  Bs[bi] + (wave + 4) * 512);
    };

    const int nt = K >> 5;
    STAGE(0, 0);
    __syncthreads();
    for (int t = 0; t < nt; ++t) {
        if (t + 1 < nt) STAGE((t + 1) & 1, (t + 1) * 32);
        const ushort* as_ = As[t & 1];
        const ushort* bs_ = Bs[t & 1];
        bf16x8 af[4], bfr[4];
#pragma unroll
        for (int m = 0; m < 4; m++)
            af[m] = *(const bf16x8*)&as_[((wm >> 4) + m) * 512 + lh * 128 + l15 * 8];
#pragma unroll
        for (int n = 0; n < 4; n++)
            bfr[n] = *(const bf16x8*)&bs_[((wn >> 4) + n) * 512 + lh * 128 + l15 * 8];
#pragma unroll
        for (int m = 0; m < 4; m++)
#pragma unroll
            for (int n = 0; n < 4; n++)
                acc[m][n] = __builtin_amdgcn_mfma_f32_16x16x32_bf16(
                    af[m], bfr[n], acc[m][n], 0, 0, 0);
        __syncthreads();
    }

    if constexpr (STORE == 2) {
#pragma unroll
        for (int m = 0; m < 4; m++) {
            const int row0 = bm + wm + m * 16 + lh * 4;
            const int bb = row0 >> 8, q = row0 & 255;
#pragma unroll
            for (int n = 0; n < 4; n++) {
                const int col = bn + wn + n * 16 + l15;
                ushort4 o;
                o.x = f2bf(acc[m][n][0] * alpha);
                o.y = f2bf(acc[m][n][1] * alpha);
                o.z = f2bf(acc[m][n][2] * alpha);
                o.w = f2bf(acc[m][n][3] * alpha);
                *(ushort4*)&Ch[(size_t)bb * N * 256 + (size_t)col * 256 + q] = o;
            }
        }
    } else if constexpr (STORE == 1) {
#pragma unroll
        for (int m = 0; m < 4; m++)
#pragma unroll
            for (int r = 0; r < 4; r++) {
                const int row = bm + wm + m * 16 + lh * 4 + r;
                const float bv = BIAS ? bias[row] : 0.f;
#pragma unroll
                for (int n = 0; n < 4; n++) {
                    const int col = bn + wn + n * 16 + l15;
                    Ch[(size_t)row * N + col] = f2bf(acc[m][n][r] * alpha + bv);
                }
            }
    } else {
#pragma unroll
        for (int m = 0; m < 4; m++)
#pragma unroll
            for (int r = 0; r < 4; r++) {
                const int row = bm + wm + m * 16 + lh * 4 + r;
                const float bv = BIAS ? bias[row] : 0.f;
#pragma unroll
                for (int n = 0; n < 4; n++) {
                    const int col = bn + wn + n * 16 + l15;
                    Cf[(size_t)row * N + col] = acc[m][n][r] * alpha + bv;
                }
            }
    }
}

// ---------------------------------------------------------------------------
// Fused attention v5 = R6 structure + 2-phase pipeline + normalized chunked P.
// Block = (b, h, q-half): 128-row q-tile, grid 512, XCD-decoded. 4 waves.
// Phase A: dbuf {Q 8KB + K 16KB} x2 at [0,48KB); prefetch tile t+1 before
//   computing t; single barrier/iter.
// Softmax: in-register; P normalized by 1/rowsum BEFORE bf16 write (no rs
//   buffer needed); Ps chunked [128]x[256] at [0,64KB). First V-tile load
//   issued before softmax (latency hides under exp/shfl VALU).
// Phase B: Vs dbuf 2x8KB at [64KB,80KB); same 2-phase schedule.
// LDS 81920 B -> 2 blocks/CU. Chunked addr: idx(row,col) =
//   (row>>4)*4096 + (col>>3)*128 + (row&15)*8 + (col&7)   [ushort units]
// ---------------------------------------------------------------------------
__global__ __launch_bounds__(256, 2) void attn_mfma(const ushort* __restrict__ qb,
                                                    const ushort* __restrict__ k1,
                                                    const ushort* __restrict__ v1T,
                                                    const int* __restrict__ vlen,
                                                    ushort* __restrict__ aout) {
    __shared__ __align__(16) ushort pool[40960];     // 80 KB
    ushort* Ps = pool;                                // chunked P, [0, 32768)

    const int bid = blockIdx.x;
    const int xcd = bid & 7, pos = bid >> 3;      // 64 blocks per XCD
    const int b = xcd * 4 + (pos >> 4);           // 4 batches per XCD
    const int inner = pos & 15;
    const int h = inner >> 1, qh = inner & 1;
    const int n = b * 8 + h;
    const int q0 = qh * 128;

    const int tid = threadIdx.x, wave = tid >> 6, l = tid & 63;
    const int l15 = l & 15, lh = l >> 4;
    const int vl = vlen[b];

    const ushort* qbase = qb  + ((size_t)n * LQc + q0) * Dc;
    const ushort* kbase = k1  + (size_t)b * LQc * Dc;
    const ushort* vbase = v1T + (size_t)b * LQc * Dc;

    // ---- phase A: scores 128x256, 2-phase dbuf --------------------------
    f32x4 sacc[2][16];
#pragma unroll
    for (int m = 0; m < 2; m++)
#pragma unroll
        for (int fn = 0; fn < 16; fn++) sacc[m][fn] = (f32x4){0.f, 0.f, 0.f, 0.f};

    auto STAGE_A = [&](int bi, int k0) {
        ushort* q_ = pool + bi * 12288;           // 24 KB per buffer
        ushort* k_ = q_ + 4096;
        gload16(qbase + (size_t)(wave * 16 + l15) * Dc + k0 + lh * 8,      q_ + wave * 512);
        gload16(qbase + (size_t)(64 + wave * 16 + l15) * Dc + k0 + lh * 8, q_ + (wave + 4) * 512);
#pragma unroll
        for (int j = 0; j < 4; j++)
            gload16(kbase + (size_t)((j * 4 + wave) * 16 + l15) * Dc + k0 + lh * 8,
                    k_ + (j * 4 + wave) * 512);
    };

    STAGE_A(0, 0);
    __syncthreads();
    for (int t = 0; t < 16; ++t) {
        if (t < 15) STAGE_A((t + 1) & 1, (t + 1) * 32);
        const ushort* q_ = pool + (t & 1) * 12288;
        const ushort* k_ = q_ + 4096;
        bf16x8 aq[2];
        aq[0] = *(const bf16x8*)&q_[(2 * wave + 0) * 512 + lh * 128 + l15 * 8];
        aq[1] = *(const bf16x8*)&q_[(2 * wave + 1) * 512 + lh * 128 + l15 * 8];
#pragma unroll
        for (int fn = 0; fn < 16; fn++) {
            bf16x8 bk = *(const bf16x8*)&k_[fn * 512 + lh * 128 + l15 * 8];
            sacc[0][fn] = __builtin_amdgcn_mfma_f32_16x16x32_bf16(aq[0], bk, sacc[0][fn], 0, 0, 0);
            sacc[1][fn] = __builtin_amdgcn_mfma_f32_16x16x32_bf16(aq[1], bk, sacc[1][fn], 0, 0, 0);
        }
        __syncthreads();
    }

    // ---- prefetch first V tile (hides under softmax VALU) ---------------
    auto STAGE_V = [&](int bi, int it) {
        const int d0 = (it >> 3) * 128, l0 = (it & 7) * 32;
        ushort* v_ = pool + 32768 + bi * 4096;
        gload16(vbase + (size_t)(d0 + wave * 16 + l15) * LQc + l0 + lh * 8,
                v_ + wave * 512);
        gload16(vbase + (size_t)(d0 + 64 + wave * 16 + l15) * LQc + l0 + lh * 8,
                v_ + (wave + 4) * 512);
    };
    STAGE_V(0, 0);

    // ---- softmax: wave owns rows [32w,32w+32); normalize before write ---
#pragma unroll
    for (int m = 0; m < 2; m++)
#pragma unroll
        for (int r = 0; r < 4; r++) {
            const int rowl = wave * 32 + m * 16 + lh * 4 + r;
            float v[16];
            float rmax = -3.4e38f;
#pragma unroll
            for (int fn = 0; fn < 16; fn++) {
                const int col = fn * 16 + l15;
                float s = sacc[m][fn][r];
                v[fn] = (col < vl) ? s : -1e6f;
                rmax = fmaxf(rmax, v[fn]);
            }
            rmax = fmaxf(rmax, __shfl_xor(rmax, 1));
            rmax = fmaxf(rmax, __shfl_xor(rmax, 2));
            rmax = fmaxf(rmax, __shfl_xor(rmax, 4));
            rmax = fmaxf(rmax, __shfl_xor(rmax, 8));
            float rsum = 0.f;
#pragma unroll
            for (int fn = 0; fn < 16; fn++) {
                v[fn] = __expf(v[fn] - rmax);
                rsum += v[fn];
            }
            rsum += __shfl_xor(rsum, 1);
            rsum += __shfl_xor(rsum, 2);
            rsum += __shfl_xor(rsum, 4);
            rsum += __shfl_xor(rsum, 8);
            const float rinv = 1.0f / rsum;
            // chunked P write: row=rowl, col=fn*16+l15
            const int base = (wave * 2 + m) * 4096 + (lh * 4 + r) * 8 + (l15 & 7);
            const int chi = (l15 >> 3) * 128;
#pragma unroll
            for (int fn = 0; fn < 16; fn++)
                Ps[base + fn * 256 + chi] = f2bf(v[fn] * rinv);
        }
    __syncthreads();   // Ps visible + V tile 0 loaded

    // ---- phase B: out = P @ V, 4 d-chunks of 128, 2-phase dbuf ----------
    int it = 0;
    for (int d0 = 0; d0 < Dc; d0 += 128) {
        f32x4 o[8][2];
#pragma unroll
        for (int qf = 0; qf < 8; qf++) {
            o[qf][0] = (f32x4){0.f, 0.f, 0.f, 0.f};
            o[qf][1] = (f32x4){0.f, 0.f, 0.f, 0.f};
        }
        for (int l0 = 0; l0 < LQc; l0 += 32, ++it) {
            if (it < 31) STAGE_V((it + 1) & 1, it + 1);
            const ushort* v_ = pool + 32768 + (it & 1) * 4096;
            bf16x8 vb[2];
            vb[0] = *(const bf16x8*)&v_[(2 * wave + 0) * 512 + lh * 128 + l15 * 8];
            vb[1] = *(const bf16x8*)&v_[(2 * wave + 1) * 512 + lh * 128 + l15 * 8];
            const int pcol = (l0 >> 3) + lh;     // chunk index of P col
#pragma unroll
            for (int qf = 0; qf < 8; qf++) {
                bf16x8 pa = *(const bf16x8*)&Ps[qf * 4096 + pcol * 128 + l15 * 8];
                o[qf][0] = __builtin_amdgcn_mfma_f32_16x16x32_bf16(pa, vb[0], o[qf][0], 0, 0, 0);
                o[qf][1] = __builtin_amdgcn_mfma_f32_16x16x32_bf16(pa, vb[1], o[qf][1], 0, 0, 0);
            }
            __syncthreads();
        }
#pragma unroll
        for (int qf = 0; qf < 8; qf++)
#pragma unroll
            for (int r = 0; r < 4; r++) {
                const int rowl = qf * 16 + lh * 4 + r;
#pragma unroll
                for (int df = 0; df < 2; df++) {
                    const int col = d0 + wave * 32 + df * 16 + l15;
                    aout[((size_t)n * LQc + q0 + rowl) * Dc + col] =
                        f2bf(o[qf][df][r]);
                }
            }
    }
}

// ---------------------------------------------------------------------------
extern "C" void kernel_launch(void* const* d_in, const int* in_sizes, int n_in,
                              void* d_out, int out_size, void* d_ws, size_t ws_size,
                              hipStream_t stream) {
    const float* queries    = (const float*)d_in[0];
    const float* keys       = (const float*)d_in[1];
    const float* values     = (const float*)d_in[2];
    const float* W_q        = (const float*)d_in[3];
    const float* W_k        = (const float*)d_in[4];
    const float* W_v        = (const float*)d_in[5];
    const float* W_o        = (const float*)d_in[6];
    const float* W_len      = (const float*)d_in[7];
    const float* b_len      = (const float*)d_in[8];
    const int*   valid_lens = (const int*)d_in[9];

    char* ws = (char*)d_ws;
    const size_t MB = 1024 * 1024;
    ushort* qb      = (ushort*)ws;                    // 64 MB
    ushort* keysT   = (ushort*)(ws + 64 * MB);        // 32 MB
    ushort* valsT   = (ushort*)(ws + 96 * MB);        // 32 MB
    ushort* qconv   = keysT;                          // aliases keysT+valsT (64 MB)
    ushort* attnout = keysT;                          // aliases same region
    ushort* wq = (ushort*)(ws + 128 * MB);            // 5 x 512 KB consecutive
    ushort* wk = wq + 262144;
    ushort* wv = wk + 262144;
    ushort* wo = wv + 262144;
    ushort* wl = wo + 262144;
    ushort* t1  = wl + 262144;                        // 4 Mi elems (8 MB)
    ushort* k1  = t1 + 4194304;
    ushort* v1T = k1 + 4194304;

    const float alpha_q = 0.044194173824159216f;      // 1/sqrt(512)
    dim3 blk(256);

    // all 5 weights -> bf16 in one launch
    cvt_w<<<1280, blk, 0, stream>>>(W_q, W_k, W_v, W_o, W_len, wq);

    // transpose+convert keys/values: [b][1024][512] f32 -> [b][512][1024] bf16
    transpose_cvt<<<dim3(32, 16, 32), blk, 0, stream>>>(keys,   keysT, LVc, Dc);
    transpose_cvt<<<dim3(32, 16, 32), blk, 0, stream>>>(values, valsT, LVc, Dc);

    // k path: t1 = W_len @ keys + b_len ; k1 = t1 @ W_k^T
    gemm_bt<1, true, 0><<<dim3(4, 2, 32), blk, 0, stream>>>(
        wl, keysT, t1, b_len, 256, 512, 1024, 1.f, 0, 524288, 131072, 0);
    gemm_bt<1, false, 1><<<dim3(256), blk, 0, stream>>>(
        t1, wk, k1, nullptr, 8192, 512, 512, 1.f, 0, 0, 0, 8);

    // v path: t1 = W_len @ values + b_len ; v1T = (t1 @ W_v^T)^T per batch
    gemm_bt<1, true, 0><<<dim3(4, 2, 32), blk, 0, stream>>>(
        wl, valsT, t1, b_len, 256, 512, 1024, 1.f, 0, 524288, 131072, 0);
    gemm_bt<2, false, 1><<<dim3(256), blk, 0, stream>>>(
        t1, wv, v1T, nullptr, 8192, 512, 512, 1.f, 0, 0, 0, 8);

    // q path: convert queries, project (scale folded in)
    cvt_bf16<<<2048, blk, 0, stream>>>(queries, qconv, 8388608);
    gemm_bt<1, false, 1><<<dim3(2048), blk, 0, stream>>>(
        qconv, wq, qb, nullptr, 65536, 512, 512, alpha_q, 0, 0, 0, 64);

    // attention (overwrites qconv region with attn_out)
    attn_mfma<<<dim3(512), blk, 0, stream>>>(qb, k1, v1T, valid_lens, attnout);

    // output projection -> fp32 d_out
    gemm_bt<0, false, 1><<<dim3(2048), blk, 0, stream>>>(
        attnout, wo, d_out, nullptr, 65536, 512, 512, 1.f, 0, 0, 0, 64);
}

// Round 9
// 360.314 us; speedup vs baseline: 1.1008x; 1.1008x over previous
//
#include <hip/hip_runtime.h>
#include <math.h>

#define Bc  32
#define Hc  8
#define LQc 256
#define LVc 1024
#define Dc  512

typedef short bf16x8 __attribute__((ext_vector_type(8)));
typedef float f32x4  __attribute__((ext_vector_type(4)));

__device__ __forceinline__ unsigned short f2bf(float x) {   // RNE fp32->bf16
    unsigned u = __builtin_bit_cast(unsigned, x);
    u = (u + 0x7fffu + ((u >> 16) & 1u)) >> 16;
    return (unsigned short)u;
}

__device__ __forceinline__ void gload16(const ushort* g, ushort* l) {
    __builtin_amdgcn_global_load_lds(
        (const __attribute__((address_space(1))) unsigned*)g,
        (__attribute__((address_space(3))) unsigned*)l, 16, 0, 0);
}

// ---------------------------------------------------------------------------
// fp32 -> bf16 elementwise convert (vectorized float4 / ushort4)
// ---------------------------------------------------------------------------
__global__ __launch_bounds__(256) void cvt_bf16(const float* __restrict__ in,
                                                ushort* __restrict__ out, int n4) {
    int i = blockIdx.x * 256 + threadIdx.x;
    const int stride = gridDim.x * 256;
    for (; i < n4; i += stride) {
        float4 v = ((const float4*)in)[i];
        ushort4 o;
        o.x = f2bf(v.x); o.y = f2bf(v.y); o.z = f2bf(v.z); o.w = f2bf(v.w);
        ((ushort4*)out)[i] = o;
    }
}

// ---------------------------------------------------------------------------
// fp32 [b][L][D] -> bf16 [b][D][L] transpose+convert, 32x32 LDS tiles
// ---------------------------------------------------------------------------
__global__ __launch_bounds__(256) void transpose_cvt(const float* __restrict__ in,
                                                     ushort* __restrict__ out,
                                                     int L, int D) {
    __shared__ float t[32][33];
    const int b = blockIdx.z;
    const int l0 = blockIdx.x * 32, d0 = blockIdx.y * 32;
    in  += (size_t)b * L * D;
    out += (size_t)b * L * D;
    const int r = threadIdx.x >> 5, c = threadIdx.x & 31;
#pragma unroll
    for (int i = 0; i < 4; i++)
        t[r + 8 * i][c] = in[(size_t)(l0 + r + 8 * i) * D + d0 + c];
    __syncthreads();
#pragma unroll
    for (int i = 0; i < 4; i++)
        out[(size_t)(d0 + r + 8 * i) * L + l0 + c] = f2bf(t[c][r + 8 * i]);
}

// ---------------------------------------------------------------------------
// C[m,n] = alpha * sum_k A[m,k]*B[n,k] (+ bias)         (bf16 in, f32 accum)
// 128x128 tile, BK=32, 4 waves (2x2), 4x4 16x16x32 frags per wave.
// (R6-proven version: linear LDS, coalesced 4-lane-per-row staging.)
// STORE: 0 = f32 row-major, 1 = bf16 row-major, 2 = bf16 transposed with
//        256-row batches: out[(m>>8)][n][m&255]  (for t1v^T); bias[m&255]
// SWIZ:  1 = 1D grid, XCD-grouped decode
// ---------------------------------------------------------------------------
template <int STORE, bool BIAS, int SWIZ>
__global__ __launch_bounds__(256) void gemm_bt(const ushort* __restrict__ A,
                                               const ushort* __restrict__ B,
                                               void* __restrict__ Cv,
                                               const float* __restrict__ bias,
                                               int M, int N, int K, float alpha,
                                               long sA, long sB, long sC,
                                               int byPerXcd) {
    __shared__ ushort As[128 * 32];
    __shared__ ushort Bs[128 * 32];
    const int z = blockIdx.z;
    A += (size_t)z * sA;
    B += (size_t)z * sB;
    float*  Cf = (float*)Cv  + (size_t)z * sC;
    ushort* Ch = (ushort*)Cv + (size_t)z * sC;

    int bm, bn;
    if constexpr (SWIZ) {
        const int bid = blockIdx.x;
        const int xcd = bid & 7, slot = bid >> 3;
        bm = (xcd * byPerXcd + (slot >> 2)) * 128;
        bn = (slot & 3) * 128;
    } else {
        bm = blockIdx.y * 128;
        bn = blockIdx.x * 128;
    }
    const int tid = threadIdx.x;
    const int wave = tid >> 6, l = tid & 63;
    const int wm = (wave >> 1) * 64, wn = (wave & 1) * 64;
    const int l15 = l & 15, lh = l >> 4;

    f32x4 acc[4][4];
#pragma unroll
    for (int m = 0; m < 4; m++)
#pragma unroll
        for (int n = 0; n < 4; n++) acc[m][n] = (f32x4){0.f, 0.f, 0.f, 0.f};

    const int srow = tid >> 2, scol = (tid & 3) * 8;
    ushort* ldsA = As + (wave * 16) * 32;
    ushort* ldsB = Bs + (wave * 16) * 32;
    const ushort* gA = A + (size_t)(bm + srow) * K + scol;
    const ushort* gB = B + (size_t)(bn + srow) * K + scol;

    for (int k0 = 0; k0 < K; k0 += 32) {
        gload16(gA + k0, ldsA);
        gload16(gA + k0 + (size_t)64 * K, ldsA + 64 * 32);
        gload16(gB + k0, ldsB);
        gload16(gB + k0 + (size_t)64 * K, ldsB + 64 * 32);
        __syncthreads();
        bf16x8 af[4], bfr[4];
#pragma unroll
        for (int m = 0; m < 4; m++)
            af[m] = *(const bf16x8*)&As[(wm + m * 16 + l15) * 32 + lh * 8];
#pragma unroll
        for (int n = 0; n < 4; n++)
            bfr[n] = *(const bf16x8*)&Bs[(wn + n * 16 + l15) * 32 + lh * 8];
#pragma unroll
        for (int m = 0; m < 4; m++)
#pragma unroll
            for (int n = 0; n < 4; n++)
                acc[m][n] = __builtin_amdgcn_mfma_f32_16x16x32_bf16(
                    af[m], bfr[n], acc[m][n], 0, 0, 0);
        __syncthreads();
    }

    if constexpr (STORE == 2) {
#pragma unroll
        for (int m = 0; m < 4; m++) {
            const int row0 = bm + wm + m * 16 + lh * 4;
            const int bb = row0 >> 8, q = row0 & 255;
            float bv[4] = {0.f, 0.f, 0.f, 0.f};
            if constexpr (BIAS) {
#pragma unroll
                for (int r = 0; r < 4; r++) bv[r] = bias[q + r];
            }
#pragma unroll
            for (int n = 0; n < 4; n++) {
                const int col = bn + wn + n * 16 + l15;
                ushort4 o;
                o.x = f2bf(acc[m][n][0] * alpha + bv[0]);
                o.y = f2bf(acc[m][n][1] * alpha + bv[1]);
                o.z = f2bf(acc[m][n][2] * alpha + bv[2]);
                o.w = f2bf(acc[m][n][3] * alpha + bv[3]);
                *(ushort4*)&Ch[(size_t)bb * N * 256 + (size_t)col * 256 + q] = o;
            }
        }
    } else if constexpr (STORE == 1) {
#pragma unroll
        for (int m = 0; m < 4; m++)
#pragma unroll
            for (int r = 0; r < 4; r++) {
                const int row = bm + wm + m * 16 + lh * 4 + r;
                const float bv = BIAS ? bias[row & 255] : 0.f;
#pragma unroll
                for (int n = 0; n < 4; n++) {
                    const int col = bn + wn + n * 16 + l15;
                    Ch[(size_t)row * N + col] = f2bf(acc[m][n][r] * alpha + bv);
                }
            }
    } else {
#pragma unroll
        for (int m = 0; m < 4; m++)
#pragma unroll
            for (int r = 0; r < 4; r++) {
                const int row = bm + wm + m * 16 + lh * 4 + r;
                const float bv = BIAS ? bias[row & 255] : 0.f;
#pragma unroll
                for (int n = 0; n < 4; n++) {
                    const int col = bn + wn + n * 16 + l15;
                    Cf[(size_t)row * N + col] = acc[m][n][r] * alpha + bv;
                }
            }
    }
}

// ---------------------------------------------------------------------------
// Fused attention (R6-proven v4): 128-row q-tile, grid 512, XCD-decoded,
// chunked conflict-free LDS for Q/K/V staging. 4 waves.
// ---------------------------------------------------------------------------
__global__ __launch_bounds__(256, 2) void attn_mfma(const ushort* __restrict__ qb,
                                                    const ushort* __restrict__ k1,
                                                    const ushort* __restrict__ v1T,
                                                    const int* __restrict__ vlen,
                                                    ushort* __restrict__ aout) {
    __shared__ __align__(16) char pool[76288];
    ushort* Qs = (ushort*)pool;              // 8 groups  (8 KB, phase A)
    ushort* Ks = (ushort*)(pool + 8192);     // 16 groups (16 KB, phase A)
    ushort* Ps = (ushort*)pool;              // [128][264] 67584 B (phase B)
    ushort* Vs = (ushort*)(pool + 67584);    // 8 groups  (8 KB, phase B)
    float*  rs = (float*)(pool + 75776);     // [128] row sums

    const int bid = blockIdx.x;
    const int xcd = bid & 7, pos = bid >> 3;      // 64 blocks per XCD
    const int b = xcd * 4 + (pos >> 4);           // 4 batches per XCD
    const int inner = pos & 15;
    const int h = inner >> 1, qh = inner & 1;
    const int n = b * 8 + h;
    const int q0 = qh * 128;

    const int tid = threadIdx.x, wave = tid >> 6, l = tid & 63;
    const int l15 = l & 15, lh = l >> 4;
    const int vl = vlen[b];

    const ushort* qbase = qb  + ((size_t)n * LQc + q0) * Dc;
    const ushort* kbase = k1  + (size_t)b * LQc * Dc;
    const ushort* vbase = v1T + (size_t)b * LQc * Dc;

    // ---- phase A: scores 128x256 ---------------------------------------
    f32x4 sacc[2][16];
#pragma unroll
    for (int m = 0; m < 2; m++)
#pragma unroll
        for (int fn = 0; fn < 16; fn++) sacc[m][fn] = (f32x4){0.f, 0.f, 0.f, 0.f};

    for (int k0 = 0; k0 < Dc; k0 += 32) {
        gload16(qbase + (size_t)(wave * 16 + l15) * Dc + k0 + lh * 8,      Qs + wave * 512);
        gload16(qbase + (size_t)(64 + wave * 16 + l15) * Dc + k0 + lh * 8, Qs + (wave + 4) * 512);
#pragma unroll
        for (int j = 0; j < 4; j++)
            gload16(kbase + (size_t)((j * 4 + wave) * 16 + l15) * Dc + k0 + lh * 8,
                    Ks + (j * 4 + wave) * 512);
        __syncthreads();
        bf16x8 aq[2];
        aq[0] = *(const bf16x8*)&Qs[(2 * wave + 0) * 512 + lh * 128 + l15 * 8];
        aq[1] = *(const bf16x8*)&Qs[(2 * wave + 1) * 512 + lh * 128 + l15 * 8];
#pragma unroll
        for (int fn = 0; fn < 16; fn++) {
            bf16x8 bk = *(const bf16x8*)&Ks[fn * 512 + lh * 128 + l15 * 8];
            sacc[0][fn] = __builtin_amdgcn_mfma_f32_16x16x32_bf16(aq[0], bk, sacc[0][fn], 0, 0, 0);
            sacc[1][fn] = __builtin_amdgcn_mfma_f32_16x16x32_bf16(aq[1], bk, sacc[1][fn], 0, 0, 0);
        }
        __syncthreads();
    }

    // ---- softmax: wave owns rows [32w, 32w+32) --------------------------
#pragma unroll
    for (int m = 0; m < 2; m++)
#pragma unroll
        for (int r = 0; r < 4; r++) {
            const int rowl = wave * 32 + m * 16 + lh * 4 + r;
            float v[16];
            float rmax = -3.4e38f;
#pragma unroll
            for (int fn = 0; fn < 16; fn++) {
                const int col = fn * 16 + l15;
                float s = sacc[m][fn][r];
                v[fn] = (col < vl) ? s : -1e6f;
                rmax = fmaxf(rmax, v[fn]);
            }
            rmax = fmaxf(rmax, __shfl_xor(rmax, 1));
            rmax = fmaxf(rmax, __shfl_xor(rmax, 2));
            rmax = fmaxf(rmax, __shfl_xor(rmax, 4));
            rmax = fmaxf(rmax, __shfl_xor(rmax, 8));
            float rsum = 0.f;
#pragma unroll
            for (int fn = 0; fn < 16; fn++) {
                v[fn] = __expf(v[fn] - rmax);
                rsum += v[fn];
            }
            rsum += __shfl_xor(rsum, 1);
            rsum += __shfl_xor(rsum, 2);
            rsum += __shfl_xor(rsum, 4);
            rsum += __shfl_xor(rsum, 8);
#pragma unroll
            for (int fn = 0; fn < 16; fn++)
                Ps[rowl * 264 + fn * 16 + l15] = f2bf(v[fn]);
            if (l15 == 0) rs[rowl] = rsum;
        }
    __syncthreads();

    // ---- phase B: out = P @ V, 4 chunks of 128 d-cols --------------------
    for (int d0 = 0; d0 < Dc; d0 += 128) {
        f32x4 o[8][2];
#pragma unroll
        for (int qf = 0; qf < 8; qf++)
#pragma unroll
            for (int df = 0; df < 2; df++) o[qf][df] = (f32x4){0.f, 0.f, 0.f, 0.f};

        for (int l0 = 0; l0 < LQc; l0 += 32) {
            gload16(vbase + (size_t)(d0 + wave * 16 + l15) * LQc + l0 + lh * 8,
                    Vs + wave * 512);
            gload16(vbase + (size_t)(d0 + 64 + wave * 16 + l15) * LQc + l0 + lh * 8,
                    Vs + (wave + 4) * 512);
            __syncthreads();
            bf16x8 vb[2];
            vb[0] = *(const bf16x8*)&Vs[(2 * wave + 0) * 512 + lh * 128 + l15 * 8];
            vb[1] = *(const bf16x8*)&Vs[(2 * wave + 1) * 512 + lh * 128 + l15 * 8];
#pragma unroll
            for (int qf = 0; qf < 8; qf++) {
                bf16x8 pa = *(const bf16x8*)&Ps[(qf * 16 + l15) * 264 + l0 + lh * 8];
                o[qf][0] = __builtin_amdgcn_mfma_f32_16x16x32_bf16(pa, vb[0], o[qf][0], 0, 0, 0);
                o[qf][1] = __builtin_amdgcn_mfma_f32_16x16x32_bf16(pa, vb[1], o[qf][1], 0, 0, 0);
            }
            __syncthreads();
        }
#pragma unroll
        for (int qf = 0; qf < 8; qf++)
#pragma unroll
            for (int r = 0; r < 4; r++) {
                const int rowl = qf * 16 + lh * 4 + r;
                const float rinv = 1.0f / rs[rowl];
#pragma unroll
                for (int df = 0; df < 2; df++) {
                    const int col = d0 + wave * 32 + df * 16 + l15;
                    aout[((size_t)n * LQc + q0 + rowl) * Dc + col] =
                        f2bf(o[qf][df][r] * rinv);
                }
            }
    }
}

// ---------------------------------------------------------------------------
extern "C" void kernel_launch(void* const* d_in, const int* in_sizes, int n_in,
                              void* d_out, int out_size, void* d_ws, size_t ws_size,
                              hipStream_t stream) {
    const float* queries    = (const float*)d_in[0];
    const float* keys       = (const float*)d_in[1];
    const float* values     = (const float*)d_in[2];
    const float* W_q        = (const float*)d_in[3];
    const float* W_k        = (const float*)d_in[4];
    const float* W_v        = (const float*)d_in[5];
    const float* W_o        = (const float*)d_in[6];
    const float* W_len      = (const float*)d_in[7];
    const float* b_len      = (const float*)d_in[8];
    const int*   valid_lens = (const int*)d_in[9];

    char* ws = (char*)d_ws;
    const size_t MB = 1024 * 1024;
    ushort* qb      = (ushort*)ws;                    // 64 MB
    ushort* keysT   = (ushort*)(ws + 64 * MB);        // 32 MB
    ushort* valsT   = (ushort*)(ws + 96 * MB);        // 32 MB
    ushort* qconv   = keysT;                          // aliases keysT+valsT (64 MB)
    ushort* attnout = keysT;                          // aliases same region
    ushort* woBf = (ushort*)(ws + 128 * MB);          // 7 x 512 KB consecutive
    ushort* wl   = woBf + 262144;
    ushort* wqT  = wl   + 262144;
    ushort* wkT  = wqT  + 262144;
    ushort* wvT  = wkT  + 262144;
    ushort* Et   = wvT  + 262144;                     // S^T fold: qE B-operand
    ushort* G    = Et   + 262144;                     // W_o @ W_v fold
    ushort* t1k  = G    + 262144;                     // [32][256][512] bf16, 8 MB
    ushort* t1vT = t1k  + 4194304;                    // [32][512][256] bf16, 8 MB

    const float alpha_q = 0.044194173824159216f;      // 1/sqrt(512)
    dim3 blk(256);

    // ---- weight prep: bf16 copies / transposes + folded products --------
    cvt_bf16<<<64, blk, 0, stream>>>(W_o,   woBf, 65536);
    cvt_bf16<<<64, blk, 0, stream>>>(W_len, wl,   65536);
    transpose_cvt<<<dim3(16, 16, 1), blk, 0, stream>>>(W_q, wqT, 512, 512);
    transpose_cvt<<<dim3(16, 16, 1), blk, 0, stream>>>(W_k, wkT, 512, 512);
    transpose_cvt<<<dim3(16, 16, 1), blk, 0, stream>>>(W_v, wvT, 512, 512);
    // Et[c][d] = sum_e W_k[e,c] * W_q[e,d]   (so scores = (q @ Et^T) @ t1k^T)
    gemm_bt<1, false, 0><<<dim3(4, 4, 1), blk, 0, stream>>>(
        wkT, wqT, Et, nullptr, 512, 512, 512, 1.f, 0, 0, 0, 0);
    // G[e][c] = sum_d W_o[e,d] * W_v[d,c]    (so out = pv @ G^T)
    gemm_bt<1, false, 0><<<dim3(4, 4, 1), blk, 0, stream>>>(
        woBf, wvT, G, nullptr, 512, 512, 512, 1.f, 0, 0, 0, 0);

    // ---- keys/values: transpose+convert, then length-projection ---------
    transpose_cvt<<<dim3(32, 16, 32), blk, 0, stream>>>(keys,   keysT, LVc, Dc);
    transpose_cvt<<<dim3(32, 16, 32), blk, 0, stream>>>(values, valsT, LVc, Dc);

    // t1k[b][q][d] = W_len @ keys_b + b_len          (row-major)
    gemm_bt<1, true, 0><<<dim3(4, 2, 32), blk, 0, stream>>>(
        wl, keysT, t1k, b_len, 256, 512, 1024, 1.f, 0, 524288, 131072, 0);
    // t1vT[b][d][q] = (W_len @ values_b + b_len)^T   (transposed store + bias)
    gemm_bt<2, true, 0><<<dim3(4, 2, 32), blk, 0, stream>>>(
        wl, valsT, t1vT, b_len, 256, 512, 1024, 1.f, 0, 524288, 131072, 0);

    // ---- q path: cvt then project with folded Et (scale folded in) ------
    cvt_bf16<<<2048, blk, 0, stream>>>(queries, qconv, 8388608);
    gemm_bt<1, false, 1><<<dim3(2048), blk, 0, stream>>>(
        qconv, Et, qb, nullptr, 65536, 512, 512, alpha_q, 0, 0, 0, 64);

    // ---- attention: scores=qb@t1k^T, softmax+mask, pv=P@t1v -------------
    attn_mfma<<<dim3(512), blk, 0, stream>>>(qb, t1k, t1vT, valid_lens, attnout);

    // ---- output projection with folded G -> fp32 d_out ------------------
    gemm_bt<0, false, 1><<<dim3(2048), blk, 0, stream>>>(
        attnout, G, d_out, nullptr, 65536, 512, 512, 1.f, 0, 0, 0, 64);
}

// Round 12
// 351.180 us; speedup vs baseline: 1.1295x; 1.0260x over previous
//
#include <hip/hip_runtime.h>
#include <math.h>

#define Bc  32
#define Hc  8
#define LQc 256
#define LVc 1024
#define Dc  512

// per-wave drain of outstanding global_load_lds BEFORE a barrier publishes
// the staged LDS to other waves (vmcnt is per-wave; without this the
// legalizer may defer the wait past the barrier -> cross-wave race, R10).
#define VMCNT0 asm volatile("s_waitcnt vmcnt(0)" ::: "memory")

typedef short bf16x8 __attribute__((ext_vector_type(8)));
typedef float f32x4  __attribute__((ext_vector_type(4)));

__device__ __forceinline__ unsigned short f2bf(float x) {   // RNE fp32->bf16
    unsigned u = __builtin_bit_cast(unsigned, x);
    u = (u + 0x7fffu + ((u >> 16) & 1u)) >> 16;
    return (unsigned short)u;
}

__device__ __forceinline__ void gload16(const ushort* g, ushort* l) {
    __builtin_amdgcn_global_load_lds(
        (const __attribute__((address_space(1))) unsigned*)g,
        (__attribute__((address_space(3))) unsigned*)l, 16, 0, 0);
}

// ---------------------------------------------------------------------------
// fp32 -> bf16 elementwise convert (vectorized float4 / ushort4)
// ---------------------------------------------------------------------------
__global__ __launch_bounds__(256) void cvt_bf16(const float* __restrict__ in,
                                                ushort* __restrict__ out, int n4) {
    int i = blockIdx.x * 256 + threadIdx.x;
    const int stride = gridDim.x * 256;
    for (; i < n4; i += stride) {
        float4 v = ((const float4*)in)[i];
        ushort4 o;
        o.x = f2bf(v.x); o.y = f2bf(v.y); o.z = f2bf(v.z); o.w = f2bf(v.w);
        ((ushort4*)out)[i] = o;
    }
}

// ---------------------------------------------------------------------------
// fp32 [b][L][D] -> bf16 [b][D][L] transpose+convert, 32x32 LDS tiles
// ---------------------------------------------------------------------------
__global__ __launch_bounds__(256) void transpose_cvt(const float* __restrict__ in,
                                                     ushort* __restrict__ out,
                                                     int L, int D) {
    __shared__ float t[32][33];
    const int b = blockIdx.z;
    const int l0 = blockIdx.x * 32, d0 = blockIdx.y * 32;
    in  += (size_t)b * L * D;
    out += (size_t)b * L * D;
    const int r = threadIdx.x >> 5, c = threadIdx.x & 31;
#pragma unroll
    for (int i = 0; i < 4; i++)
        t[r + 8 * i][c] = in[(size_t)(l0 + r + 8 * i) * D + d0 + c];
    __syncthreads();
#pragma unroll
    for (int i = 0; i < 4; i++)
        out[(size_t)(d0 + r + 8 * i) * L + l0 + c] = f2bf(t[c][r + 8 * i]);
}

// ---------------------------------------------------------------------------
// C[m,n] = alpha * sum_k A[m,k]*B[n,k] (+ bias)         (bf16 in, f32 accum)
// 128x128 tile, BK=32, 4 waves (2x2), 4x4 16x16x32 frags per wave.
// (R6-proven version: linear LDS, single-buffer stage->sync->read.)
// STORE: 0 = f32 row-major, 1 = bf16 row-major, 2 = bf16 transposed with
//        256-row batches: out[(m>>8)][n][m&255]  (for t1v^T); bias[m&255]
// SWIZ:  1 = 1D grid, XCD-grouped decode
// ---------------------------------------------------------------------------
template <int STORE, bool BIAS, int SWIZ>
__global__ __launch_bounds__(256) void gemm_bt(const ushort* __restrict__ A,
                                               const ushort* __restrict__ B,
                                               void* __restrict__ Cv,
                                               const float* __restrict__ bias,
                                               int M, int N, int K, float alpha,
                                               long sA, long sB, long sC,
                                               int byPerXcd) {
    __shared__ ushort As[128 * 32];
    __shared__ ushort Bs[128 * 32];
    const int z = blockIdx.z;
    A += (size_t)z * sA;
    B += (size_t)z * sB;
    float*  Cf = (float*)Cv  + (size_t)z * sC;
    ushort* Ch = (ushort*)Cv + (size_t)z * sC;

    int bm, bn;
    if constexpr (SWIZ) {
        const int bid = blockIdx.x;
        const int xcd = bid & 7, slot = bid >> 3;
        bm = (xcd * byPerXcd + (slot >> 2)) * 128;
        bn = (slot & 3) * 128;
    } else {
        bm = blockIdx.y * 128;
        bn = blockIdx.x * 128;
    }
    const int tid = threadIdx.x;
    const int wave = tid >> 6, l = tid & 63;
    const int wm = (wave >> 1) * 64, wn = (wave & 1) * 64;
    const int l15 = l & 15, lh = l >> 4;

    f32x4 acc[4][4];
#pragma unroll
    for (int m = 0; m < 4; m++)
#pragma unroll
        for (int n = 0; n < 4; n++) acc[m][n] = (f32x4){0.f, 0.f, 0.f, 0.f};

    const int srow = tid >> 2, scol = (tid & 3) * 8;
    ushort* ldsA = As + (wave * 16) * 32;
    ushort* ldsB = Bs + (wave * 16) * 32;
    const ushort* gA = A + (size_t)(bm + srow) * K + scol;
    const ushort* gB = B + (size_t)(bn + srow) * K + scol;

    for (int k0 = 0; k0 < K; k0 += 32) {
        gload16(gA + k0, ldsA);
        gload16(gA + k0 + (size_t)64 * K, ldsA + 64 * 32);
        gload16(gB + k0, ldsB);
        gload16(gB + k0 + (size_t)64 * K, ldsB + 64 * 32);
        VMCNT0;
        __syncthreads();
        bf16x8 af[4], bfr[4];
#pragma unroll
        for (int m = 0; m < 4; m++)
            af[m] = *(const bf16x8*)&As[(wm + m * 16 + l15) * 32 + lh * 8];
#pragma unroll
        for (int n = 0; n < 4; n++)
            bfr[n] = *(const bf16x8*)&Bs[(wn + n * 16 + l15) * 32 + lh * 8];
#pragma unroll
        for (int m = 0; m < 4; m++)
#pragma unroll
            for (int n = 0; n < 4; n++)
                acc[m][n] = __builtin_amdgcn_mfma_f32_16x16x32_bf16(
                    af[m], bfr[n], acc[m][n], 0, 0, 0);
        __syncthreads();
    }

    if constexpr (STORE == 2) {
#pragma unroll
        for (int m = 0; m < 4; m++) {
            const int row0 = bm + wm + m * 16 + lh * 4;
            const int bb = row0 >> 8, q = row0 & 255;
            float bv[4] = {0.f, 0.f, 0.f, 0.f};
            if constexpr (BIAS) {
#pragma unroll
                for (int r = 0; r < 4; r++) bv[r] = bias[q + r];
            }
#pragma unroll
            for (int n = 0; n < 4; n++) {
                const int col = bn + wn + n * 16 + l15;
                ushort4 o;
                o.x = f2bf(acc[m][n][0] * alpha + bv[0]);
                o.y = f2bf(acc[m][n][1] * alpha + bv[1]);
                o.z = f2bf(acc[m][n][2] * alpha + bv[2]);
                o.w = f2bf(acc[m][n][3] * alpha + bv[3]);
                *(ushort4*)&Ch[(size_t)bb * N * 256 + (size_t)col * 256 + q] = o;
            }
        }
    } else if constexpr (STORE == 1) {
#pragma unroll
        for (int m = 0; m < 4; m++)
#pragma unroll
            for (int r = 0; r < 4; r++) {
                const int row = bm + wm + m * 16 + lh * 4 + r;
                const float bv = BIAS ? bias[row & 255] : 0.f;
#pragma unroll
                for (int n = 0; n < 4; n++) {
                    const int col = bn + wn + n * 16 + l15;
                    Ch[(size_t)row * N + col] = f2bf(acc[m][n][r] * alpha + bv);
                }
            }
    } else {
#pragma unroll
        for (int m = 0; m < 4; m++)
#pragma unroll
            for (int r = 0; r < 4; r++) {
                const int row = bm + wm + m * 16 + lh * 4 + r;
                const float bv = BIAS ? bias[row & 255] : 0.f;
#pragma unroll
                for (int n = 0; n < 4; n++) {
                    const int col = bn + wn + n * 16 + l15;
                    Cf[(size_t)row * N + col] = acc[m][n][r] * alpha + bv;
                }
            }
    }
}

// ---------------------------------------------------------------------------
// Fused attention v5.1: v5 (2-phase dbuf, chunked LDS, in-reg normalized P)
// with explicit per-wave vmcnt(0) drain before every barrier that publishes
// DMA-staged LDS (closes the R10 cross-wave race).
// ---------------------------------------------------------------------------
__global__ __launch_bounds__(256, 2) void attn_mfma(const ushort* __restrict__ qb,
                                                    const ushort* __restrict__ k1,
                                                    const ushort* __restrict__ v1T,
                                                    const int* __restrict__ vlen,
                                                    ushort* __restrict__ aout) {
    __shared__ __align__(16) ushort pool[40960];     // 80 KB
    ushort* Ps = pool;                                // chunked P, [0, 32768)

    const int bid = blockIdx.x;
    const int xcd = bid & 7, pos = bid >> 3;      // 64 blocks per XCD
    const int b = xcd * 4 + (pos >> 4);           // 4 batches per XCD
    const int inner = pos & 15;
    const int h = inner >> 1, qh = inner & 1;
    const int n = b * 8 + h;
    const int q0 = qh * 128;

    const int tid = threadIdx.x, wave = tid >> 6, l = tid & 63;
    const int l15 = l & 15, lh = l >> 4;
    const int vl = vlen[b];

    const ushort* qbase = qb  + ((size_t)n * LQc + q0) * Dc;
    const ushort* kbase = k1  + (size_t)b * LQc * Dc;
    const ushort* vbase = v1T + (size_t)b * LQc * Dc;

    // ---- phase A: scores 128x256, 2-phase dbuf --------------------------
    f32x4 sacc[2][16];
#pragma unroll
    for (int m = 0; m < 2; m++)
#pragma unroll
        for (int fn = 0; fn < 16; fn++) sacc[m][fn] = (f32x4){0.f, 0.f, 0.f, 0.f};

    auto STAGE_A = [&](int bi, int k0) {
        ushort* q_ = pool + bi * 12288;           // 24 KB per buffer
        ushort* k_ = q_ + 4096;
        gload16(qbase + (size_t)(wave * 16 + l15) * Dc + k0 + lh * 8,      q_ + wave * 512);
        gload16(qbase + (size_t)(64 + wave * 16 + l15) * Dc + k0 + lh * 8, q_ + (wave + 4) * 512);
#pragma unroll
        for (int j = 0; j < 4; j++)
            gload16(kbase + (size_t)((j * 4 + wave) * 16 + l15) * Dc + k0 + lh * 8,
                    k_ + (j * 4 + wave) * 512);
    };

    STAGE_A(0, 0);
    VMCNT0;
    __syncthreads();
    for (int t = 0; t < 16; ++t) {
        if (t < 15) STAGE_A((t + 1) & 1, (t + 1) * 32);
        const ushort* q_ = pool + (t & 1) * 12288;
        const ushort* k_ = q_ + 4096;
        bf16x8 aq[2];
        aq[0] = *(const bf16x8*)&q_[(2 * wave + 0) * 512 + lh * 128 + l15 * 8];
        aq[1] = *(const bf16x8*)&q_[(2 * wave + 1) * 512 + lh * 128 + l15 * 8];
#pragma unroll
        for (int fn = 0; fn < 16; fn++) {
            bf16x8 bk = *(const bf16x8*)&k_[fn * 512 + lh * 128 + l15 * 8];
            sacc[0][fn] = __builtin_amdgcn_mfma_f32_16x16x32_bf16(aq[0], bk, sacc[0][fn], 0, 0, 0);
            sacc[1][fn] = __builtin_amdgcn_mfma_f32_16x16x32_bf16(aq[1], bk, sacc[1][fn], 0, 0, 0);
        }
        VMCNT0;            // drain STAGE_A(t+1) before publishing via barrier
        __syncthreads();
    }

    // ---- prefetch first V tile (hides under softmax VALU) ---------------
    auto STAGE_V = [&](int bi, int it) {
        const int d0 = (it >> 3) * 128, l0 = (it & 7) * 32;
        ushort* v_ = pool + 32768 + bi * 4096;
        gload16(vbase + (size_t)(d0 + wave * 16 + l15) * LQc + l0 + lh * 8,
                v_ + wave * 512);
        gload16(vbase + (size_t)(d0 + 64 + wave * 16 + l15) * LQc + l0 + lh * 8,
                v_ + (wave + 4) * 512);
    };
    STAGE_V(0, 0);

    // ---- softmax: wave owns rows [32w,32w+32); normalize before write ---
#pragma unroll
    for (int m = 0; m < 2; m++)
#pragma unroll
        for (int r = 0; r < 4; r++) {
            float v[16];
            float rmax = -3.4e38f;
#pragma unroll
            for (int fn = 0; fn < 16; fn++) {
                const int col = fn * 16 + l15;
                float s = sacc[m][fn][r];
                v[fn] = (col < vl) ? s : -1e6f;
                rmax = fmaxf(rmax, v[fn]);
            }
            rmax = fmaxf(rmax, __shfl_xor(rmax, 1));
            rmax = fmaxf(rmax, __shfl_xor(rmax, 2));
            rmax = fmaxf(rmax, __shfl_xor(rmax, 4));
            rmax = fmaxf(rmax, __shfl_xor(rmax, 8));
            float rsum = 0.f;
#pragma unroll
            for (int fn = 0; fn < 16; fn++) {
                v[fn] = __expf(v[fn] - rmax);
                rsum += v[fn];
            }
            rsum += __shfl_xor(rsum, 1);
            rsum += __shfl_xor(rsum, 2);
            rsum += __shfl_xor(rsum, 4);
            rsum += __shfl_xor(rsum, 8);
            const float rinv = 1.0f / rsum;
            // chunked P write: row = wave*32+m*16+lh*4+r, col = fn*16+l15
            const int base = (wave * 2 + m) * 4096 + (lh * 4 + r) * 8 + (l15 & 7);
            const int chi = (l15 >> 3) * 128;
#pragma unroll
            for (int fn = 0; fn < 16; fn++)
                Ps[base + fn * 256 + chi] = f2bf(v[fn] * rinv);
        }
    VMCNT0;                // drain STAGE_V(0,0) before publishing
    __syncthreads();       // Ps visible + V tile 0 loaded

    // ---- phase B: out = P @ V, 4 d-chunks of 128, 2-phase dbuf ----------
    int it = 0;
    for (int d0 = 0; d0 < Dc; d0 += 128) {
        f32x4 o[8][2];
#pragma unroll
        for (int qf = 0; qf < 8; qf++) {
            o[qf][0] = (f32x4){0.f, 0.f, 0.f, 0.f};
            o[qf][1] = (f32x4){0.f, 0.f, 0.f, 0.f};
        }
        for (int l0 = 0; l0 < LQc; l0 += 32, ++it) {
            if (it < 31) STAGE_V((it + 1) & 1, it + 1);
            const ushort* v_ = pool + 32768 + (it & 1) * 4096;
            bf16x8 vb[2];
            vb[0] = *(const bf16x8*)&v_[(2 * wave + 0) * 512 + lh * 128 + l15 * 8];
            vb[1] = *(const bf16x8*)&v_[(2 * wave + 1) * 512 + lh * 128 + l15 * 8];
            const int pcol = (l0 >> 3) + lh;     // chunk index of P col
#pragma unroll
            for (int qf = 0; qf < 8; qf++) {
                bf16x8 pa = *(const bf16x8*)&Ps[qf * 4096 + pcol * 128 + l15 * 8];
                o[qf][0] = __builtin_amdgcn_mfma_f32_16x16x32_bf16(pa, vb[0], o[qf][0], 0, 0, 0);
                o[qf][1] = __builtin_amdgcn_mfma_f32_16x16x32_bf16(pa, vb[1], o[qf][1], 0, 0, 0);
            }
            VMCNT0;        // drain STAGE_V(it+1) before publishing
            __syncthreads();
        }
#pragma unroll
        for (int qf = 0; qf < 8; qf++)
#pragma unroll
            for (int r = 0; r < 4; r++) {
                const int rowl = qf * 16 + lh * 4 + r;
#pragma unroll
                for (int df = 0; df < 2; df++) {
                    const int col = d0 + wave * 32 + df * 16 + l15;
                    aout[((size_t)n * LQc + q0 + rowl) * Dc + col] =
                        f2bf(o[qf][df][r]);
                }
            }
    }
}

// ---------------------------------------------------------------------------
extern "C" void kernel_launch(void* const* d_in, const int* in_sizes, int n_in,
                              void* d_out, int out_size, void* d_ws, size_t ws_size,
                              hipStream_t stream) {
    const float* queries    = (const float*)d_in[0];
    const float* keys       = (const float*)d_in[1];
    const float* values     = (const float*)d_in[2];
    const float* W_q        = (const float*)d_in[3];
    const float* W_k        = (const float*)d_in[4];
    const float* W_v        = (const float*)d_in[5];
    const float* W_o        = (const float*)d_in[6];
    const float* W_len      = (const float*)d_in[7];
    const float* b_len      = (const float*)d_in[8];
    const int*   valid_lens = (const int*)d_in[9];

    char* ws = (char*)d_ws;
    const size_t MB = 1024 * 1024;
    ushort* qb      = (ushort*)ws;                    // 64 MB
    ushort* keysT   = (ushort*)(ws + 64 * MB);        // 32 MB
    ushort* valsT   = (ushort*)(ws + 96 * MB);        // 32 MB
    ushort* qconv   = keysT;                          // aliases keysT+valsT (64 MB)
    ushort* attnout = keysT;                          // aliases same region
    ushort* woBf = (ushort*)(ws + 128 * MB);          // 7 x 512 KB consecutive
    ushort* wl   = woBf + 262144;
    ushort* wqT  = wl   + 262144;
    ushort* wkT  = wqT  + 262144;
    ushort* wvT  = wkT  + 262144;
    ushort* Et   = wvT  + 262144;                     // W_k^T W_q fold
    ushort* G    = Et   + 262144;                     // W_o @ W_v fold
    ushort* t1k  = G    + 262144;                     // [32][256][512] bf16, 8 MB
    ushort* t1vT = t1k  + 4194304;                    // [32][512][256] bf16, 8 MB

    const float alpha_q = 0.044194173824159216f;      // 1/sqrt(512)
    dim3 blk(256);

    // ---- weight prep: bf16 copies / transposes + folded products --------
    cvt_bf16<<<64, blk, 0, stream>>>(W_o,   woBf, 65536);
    cvt_bf16<<<64, blk, 0, stream>>>(W_len, wl,   65536);
    transpose_cvt<<<dim3(16, 16, 1), blk, 0, stream>>>(W_q, wqT, 512, 512);
    transpose_cvt<<<dim3(16, 16, 1), blk, 0, stream>>>(W_k, wkT, 512, 512);
    transpose_cvt<<<dim3(16, 16, 1), blk, 0, stream>>>(W_v, wvT, 512, 512);
    // Et[c][d] = sum_e W_k[e,c] * W_q[e,d]   (so scores = (q @ Et^T) @ t1k^T)
    gemm_bt<1, false, 0><<<dim3(4, 4, 1), blk, 0, stream>>>(
        wkT, wqT, Et, nullptr, 512, 512, 512, 1.f, 0, 0, 0, 0);
    // G[e][c] = sum_d W_o[e,d] * W_v[d,c]    (so out = pv @ G^T)
    gemm_bt<1, false, 0><<<dim3(4, 4, 1), blk, 0, stream>>>(
        woBf, wvT, G, nullptr, 512, 512, 512, 1.f, 0, 0, 0, 0);

    // ---- keys/values: transpose+convert, then length-projection ---------
    transpose_cvt<<<dim3(32, 16, 32), blk, 0, stream>>>(keys,   keysT, LVc, Dc);
    transpose_cvt<<<dim3(32, 16, 32), blk, 0, stream>>>(values, valsT, LVc, Dc);

    // t1k[b][q][d] = W_len @ keys_b + b_len          (row-major)
    gemm_bt<1, true, 0><<<dim3(4, 2, 32), blk, 0, stream>>>(
        wl, keysT, t1k, b_len, 256, 512, 1024, 1.f, 0, 524288, 131072, 0);
    // t1vT[b][d][q] = (W_len @ values_b + b_len)^T   (transposed store + bias)
    gemm_bt<2, true, 0><<<dim3(4, 2, 32), blk, 0, stream>>>(
        wl, valsT, t1vT, b_len, 256, 512, 1024, 1.f, 0, 524288, 131072, 0);

    // ---- q path: cvt then project with folded Et (scale folded in) ------
    cvt_bf16<<<2048, blk, 0, stream>>>(queries, qconv, 8388608);
    gemm_bt<1, false, 1><<<dim3(2048), blk, 0, stream>>>(
        qconv, Et, qb, nullptr, 65536, 512, 512, alpha_q, 0, 0, 0, 64);

    // ---- attention: scores=qb@t1k^T, softmax+mask, pv=P@t1v -------------
    attn_mfma<<<dim3(512), blk, 0, stream>>>(qb, t1k, t1vT, valid_lens, attnout);

    // ---- output projection with folded G -> fp32 d_out ------------------
    gemm_bt<0, false, 1><<<dim3(2048), blk, 0, stream>>>(
        attnout, G, d_out, nullptr, 65536, 512, 512, 1.f, 0, 0, 0, 64);
}

// Round 13
// 277.783 us; speedup vs baseline: 1.4279x; 1.2642x over previous
//
#include <hip/hip_runtime.h>
#include <math.h>

#define Bc  32
#define Hc  8
#define LQc 256
#define LVc 1024
#define Dc  512

// per-wave drain of outstanding global_load_lds BEFORE a barrier publishes
// the staged LDS to other waves (vmcnt is per-wave; without this the
// legalizer may defer the wait past the barrier -> cross-wave race, R10).
#define VMCNT0 asm volatile("s_waitcnt vmcnt(0)" ::: "memory")

typedef short bf16x8 __attribute__((ext_vector_type(8)));
typedef float f32x4  __attribute__((ext_vector_type(4)));

__device__ __forceinline__ unsigned short f2bf(float x) {   // RNE fp32->bf16
    unsigned u = __builtin_bit_cast(unsigned, x);
    u = (u + 0x7fffu + ((u >> 16) & 1u)) >> 16;
    return (unsigned short)u;
}

__device__ __forceinline__ void gload16(const ushort* g, ushort* l) {
    __builtin_amdgcn_global_load_lds(
        (const __attribute__((address_space(1))) unsigned*)g,
        (__attribute__((address_space(3))) unsigned*)l, 16, 0, 0);
}

// ---------------------------------------------------------------------------
// fp32 -> bf16 elementwise convert (vectorized float4 / ushort4)
// ---------------------------------------------------------------------------
__global__ __launch_bounds__(256) void cvt_bf16(const float* __restrict__ in,
                                                ushort* __restrict__ out, int n4) {
    int i = blockIdx.x * 256 + threadIdx.x;
    const int stride = gridDim.x * 256;
    for (; i < n4; i += stride) {
        float4 v = ((const float4*)in)[i];
        ushort4 o;
        o.x = f2bf(v.x); o.y = f2bf(v.y); o.z = f2bf(v.z); o.w = f2bf(v.w);
        ((ushort4*)out)[i] = o;
    }
}

// ---------------------------------------------------------------------------
// fp32 [b][L][D] -> bf16 [b][D][L] transpose+convert, 32x32 LDS tiles
// ---------------------------------------------------------------------------
__global__ __launch_bounds__(256) void transpose_cvt(const float* __restrict__ in,
                                                     ushort* __restrict__ out,
                                                     int L, int D) {
    __shared__ float t[32][33];
    const int b = blockIdx.z;
    const int l0 = blockIdx.x * 32, d0 = blockIdx.y * 32;
    in  += (size_t)b * L * D;
    out += (size_t)b * L * D;
    const int r = threadIdx.x >> 5, c = threadIdx.x & 31;
#pragma unroll
    for (int i = 0; i < 4; i++)
        t[r + 8 * i][c] = in[(size_t)(l0 + r + 8 * i) * D + d0 + c];
    __syncthreads();
#pragma unroll
    for (int i = 0; i < 4; i++)
        out[(size_t)(d0 + r + 8 * i) * L + l0 + c] = f2bf(t[c][r + 8 * i]);
}

// ---------------------------------------------------------------------------
// C[m,n] = alpha * sum_k A[m,k]*B[n,k] (+ bias)         (bf16 in, f32 accum)
// 128x128 tile, BK=32, 4 waves (2x2), 4x4 16x16x32 frags per wave.
// STORE: 0 = f32 row-major, 1 = bf16 row-major (bias[row&255]),
//        2 = bf16 transposed, 256-row batches: out[(m>>8)][n][m&255]
// SWIZ:  1 = 1D grid, XCD-grouped decode
// ---------------------------------------------------------------------------
template <int STORE, bool BIAS, int SWIZ>
__global__ __launch_bounds__(256) void gemm_bt(const ushort* __restrict__ A,
                                               const ushort* __restrict__ B,
                                               void* __restrict__ Cv,
                                               const float* __restrict__ bias,
                                               int M, int N, int K, float alpha,
                                               long sA, long sB, long sC,
                                               int byPerXcd) {
    __shared__ ushort As[128 * 32];
    __shared__ ushort Bs[128 * 32];
    const int z = blockIdx.z;
    A += (size_t)z * sA;
    B += (size_t)z * sB;
    float*  Cf = (float*)Cv  + (size_t)z * sC;
    ushort* Ch = (ushort*)Cv + (size_t)z * sC;

    int bm, bn;
    if constexpr (SWIZ) {
        const int bid = blockIdx.x;
        const int xcd = bid & 7, slot = bid >> 3;
        bm = (xcd * byPerXcd + (slot >> 2)) * 128;
        bn = (slot & 3) * 128;
    } else {
        bm = blockIdx.y * 128;
        bn = blockIdx.x * 128;
    }
    const int tid = threadIdx.x;
    const int wave = tid >> 6, l = tid & 63;
    const int wm = (wave >> 1) * 64, wn = (wave & 1) * 64;
    const int l15 = l & 15, lh = l >> 4;

    f32x4 acc[4][4];
#pragma unroll
    for (int m = 0; m < 4; m++)
#pragma unroll
        for (int n = 0; n < 4; n++) acc[m][n] = (f32x4){0.f, 0.f, 0.f, 0.f};

    const int srow = tid >> 2, scol = (tid & 3) * 8;
    ushort* ldsA = As + (wave * 16) * 32;
    ushort* ldsB = Bs + (wave * 16) * 32;
    const ushort* gA = A + (size_t)(bm + srow) * K + scol;
    const ushort* gB = B + (size_t)(bn + srow) * K + scol;

    for (int k0 = 0; k0 < K; k0 += 32) {
        gload16(gA + k0, ldsA);
        gload16(gA + k0 + (size_t)64 * K, ldsA + 64 * 32);
        gload16(gB + k0, ldsB);
        gload16(gB + k0 + (size_t)64 * K, ldsB + 64 * 32);
        VMCNT0;
        __syncthreads();
        bf16x8 af[4], bfr[4];
#pragma unroll
        for (int m = 0; m < 4; m++)
            af[m] = *(const bf16x8*)&As[(wm + m * 16 + l15) * 32 + lh * 8];
#pragma unroll
        for (int n = 0; n < 4; n++)
            bfr[n] = *(const bf16x8*)&Bs[(wn + n * 16 + l15) * 32 + lh * 8];
#pragma unroll
        for (int m = 0; m < 4; m++)
#pragma unroll
            for (int n = 0; n < 4; n++)
                acc[m][n] = __builtin_amdgcn_mfma_f32_16x16x32_bf16(
                    af[m], bfr[n], acc[m][n], 0, 0, 0);
        __syncthreads();
    }

    if constexpr (STORE == 2) {
#pragma unroll
        for (int m = 0; m < 4; m++) {
            const int row0 = bm + wm + m * 16 + lh * 4;
            const int bb = row0 >> 8, q = row0 & 255;
            float bv[4] = {0.f, 0.f, 0.f, 0.f};
            if constexpr (BIAS) {
#pragma unroll
                for (int r = 0; r < 4; r++) bv[r] = bias[q + r];
            }
#pragma unroll
            for (int n = 0; n < 4; n++) {
                const int col = bn + wn + n * 16 + l15;
                ushort4 o;
                o.x = f2bf(acc[m][n][0] * alpha + bv[0]);
                o.y = f2bf(acc[m][n][1] * alpha + bv[1]);
                o.z = f2bf(acc[m][n][2] * alpha + bv[2]);
                o.w = f2bf(acc[m][n][3] * alpha + bv[3]);
                *(ushort4*)&Ch[(size_t)bb * N * 256 + (size_t)col * 256 + q] = o;
            }
        }
    } else if constexpr (STORE == 1) {
#pragma unroll
        for (int m = 0; m < 4; m++)
#pragma unroll
            for (int r = 0; r < 4; r++) {
                const int row = bm + wm + m * 16 + lh * 4 + r;
                const float bv = BIAS ? bias[row & 255] : 0.f;
#pragma unroll
                for (int n = 0; n < 4; n++) {
                    const int col = bn + wn + n * 16 + l15;
                    Ch[(size_t)row * N + col] = f2bf(acc[m][n][r] * alpha + bv);
                }
            }
    } else {
#pragma unroll
        for (int m = 0; m < 4; m++)
#pragma unroll
            for (int r = 0; r < 4; r++) {
                const int row = bm + wm + m * 16 + lh * 4 + r;
                const float bv = BIAS ? bias[row & 255] : 0.f;
#pragma unroll
                for (int n = 0; n < 4; n++) {
                    const int col = bn + wn + n * 16 + l15;
                    Cf[(size_t)row * N + col] = acc[m][n][r] * alpha + bv;
                }
            }
    }
}

// ---------------------------------------------------------------------------
// Fused attention v6 = R12's v5.1 with FP32 direct-to-d_out output.
// scores = q(bf16 raw queries) @ k2^T (alpha folded into k2); P normalized
// in-register; out = P @ v2 via v2T -> final result, fp32, no o-proj needed.
// 2-phase dbuf, chunked conflict-free LDS, vmcnt(0)-before-barrier hardened.
// ---------------------------------------------------------------------------
__global__ __launch_bounds__(256, 2) void attn_mfma(const ushort* __restrict__ qb,
                                                    const ushort* __restrict__ k2,
                                                    const ushort* __restrict__ v2T,
                                                    const int* __restrict__ vlen,
                                                    float* __restrict__ aout) {
    __shared__ __align__(16) ushort pool[40960];     // 80 KB
    ushort* Ps = pool;                                // chunked P, [0, 32768)

    const int bid = blockIdx.x;
    const int xcd = bid & 7, pos = bid >> 3;      // 64 blocks per XCD
    const int b = xcd * 4 + (pos >> 4);           // 4 batches per XCD
    const int inner = pos & 15;
    const int h = inner >> 1, qh = inner & 1;
    const int n = b * 8 + h;
    const int q0 = qh * 128;

    const int tid = threadIdx.x, wave = tid >> 6, l = tid & 63;
    const int l15 = l & 15, lh = l >> 4;
    const int vl = vlen[b];

    const ushort* qbase = qb  + ((size_t)n * LQc + q0) * Dc;
    const ushort* kbase = k2  + (size_t)b * LQc * Dc;
    const ushort* vbase = v2T + (size_t)b * LQc * Dc;

    // ---- phase A: scores 128x256, 2-phase dbuf --------------------------
    f32x4 sacc[2][16];
#pragma unroll
    for (int m = 0; m < 2; m++)
#pragma unroll
        for (int fn = 0; fn < 16; fn++) sacc[m][fn] = (f32x4){0.f, 0.f, 0.f, 0.f};

    auto STAGE_A = [&](int bi, int k0) {
        ushort* q_ = pool + bi * 12288;           // 24 KB per buffer
        ushort* k_ = q_ + 4096;
        gload16(qbase + (size_t)(wave * 16 + l15) * Dc + k0 + lh * 8,      q_ + wave * 512);
        gload16(qbase + (size_t)(64 + wave * 16 + l15) * Dc + k0 + lh * 8, q_ + (wave + 4) * 512);
#pragma unroll
        for (int j = 0; j < 4; j++)
            gload16(kbase + (size_t)((j * 4 + wave) * 16 + l15) * Dc + k0 + lh * 8,
                    k_ + (j * 4 + wave) * 512);
    };

    STAGE_A(0, 0);
    VMCNT0;
    __syncthreads();
    for (int t = 0; t < 16; ++t) {
        if (t < 15) STAGE_A((t + 1) & 1, (t + 1) * 32);
        const ushort* q_ = pool + (t & 1) * 12288;
        const ushort* k_ = q_ + 4096;
        bf16x8 aq[2];
        aq[0] = *(const bf16x8*)&q_[(2 * wave + 0) * 512 + lh * 128 + l15 * 8];
        aq[1] = *(const bf16x8*)&q_[(2 * wave + 1) * 512 + lh * 128 + l15 * 8];
#pragma unroll
        for (int fn = 0; fn < 16; fn++) {
            bf16x8 bk = *(const bf16x8*)&k_[fn * 512 + lh * 128 + l15 * 8];
            sacc[0][fn] = __builtin_amdgcn_mfma_f32_16x16x32_bf16(aq[0], bk, sacc[0][fn], 0, 0, 0);
            sacc[1][fn] = __builtin_amdgcn_mfma_f32_16x16x32_bf16(aq[1], bk, sacc[1][fn], 0, 0, 0);
        }
        VMCNT0;            // drain STAGE_A(t+1) before publishing via barrier
        __syncthreads();
    }

    // ---- prefetch first V tile (hides under softmax VALU) ---------------
    auto STAGE_V = [&](int bi, int it) {
        const int d0 = (it >> 3) * 128, l0 = (it & 7) * 32;
        ushort* v_ = pool + 32768 + bi * 4096;
        gload16(vbase + (size_t)(d0 + wave * 16 + l15) * LQc + l0 + lh * 8,
                v_ + wave * 512);
        gload16(vbase + (size_t)(d0 + 64 + wave * 16 + l15) * LQc + l0 + lh * 8,
                v_ + (wave + 4) * 512);
    };
    STAGE_V(0, 0);

    // ---- softmax: wave owns rows [32w,32w+32); normalize before write ---
#pragma unroll
    for (int m = 0; m < 2; m++)
#pragma unroll
        for (int r = 0; r < 4; r++) {
            float v[16];
            float rmax = -3.4e38f;
#pragma unroll
            for (int fn = 0; fn < 16; fn++) {
                const int col = fn * 16 + l15;
                float s = sacc[m][fn][r];
                v[fn] = (col < vl) ? s : -1e6f;
                rmax = fmaxf(rmax, v[fn]);
            }
            rmax = fmaxf(rmax, __shfl_xor(rmax, 1));
            rmax = fmaxf(rmax, __shfl_xor(rmax, 2));
            rmax = fmaxf(rmax, __shfl_xor(rmax, 4));
            rmax = fmaxf(rmax, __shfl_xor(rmax, 8));
            float rsum = 0.f;
#pragma unroll
            for (int fn = 0; fn < 16; fn++) {
                v[fn] = __expf(v[fn] - rmax);
                rsum += v[fn];
            }
            rsum += __shfl_xor(rsum, 1);
            rsum += __shfl_xor(rsum, 2);
            rsum += __shfl_xor(rsum, 4);
            rsum += __shfl_xor(rsum, 8);
            const float rinv = 1.0f / rsum;
            // chunked P write: row = wave*32+m*16+lh*4+r, col = fn*16+l15
            const int base = (wave * 2 + m) * 4096 + (lh * 4 + r) * 8 + (l15 & 7);
            const int chi = (l15 >> 3) * 128;
#pragma unroll
            for (int fn = 0; fn < 16; fn++)
                Ps[base + fn * 256 + chi] = f2bf(v[fn] * rinv);
        }
    VMCNT0;                // drain STAGE_V(0,0) before publishing
    __syncthreads();       // Ps visible + V tile 0 loaded

    // ---- phase B: out = P @ v2, 4 d-chunks of 128, 2-phase dbuf ---------
    int it = 0;
    for (int d0 = 0; d0 < Dc; d0 += 128) {
        f32x4 o[8][2];
#pragma unroll
        for (int qf = 0; qf < 8; qf++) {
            o[qf][0] = (f32x4){0.f, 0.f, 0.f, 0.f};
            o[qf][1] = (f32x4){0.f, 0.f, 0.f, 0.f};
        }
        for (int l0 = 0; l0 < LQc; l0 += 32, ++it) {
            if (it < 31) STAGE_V((it + 1) & 1, it + 1);
            const ushort* v_ = pool + 32768 + (it & 1) * 4096;
            bf16x8 vb[2];
            vb[0] = *(const bf16x8*)&v_[(2 * wave + 0) * 512 + lh * 128 + l15 * 8];
            vb[1] = *(const bf16x8*)&v_[(2 * wave + 1) * 512 + lh * 128 + l15 * 8];
            const int pcol = (l0 >> 3) + lh;     // chunk index of P col
#pragma unroll
            for (int qf = 0; qf < 8; qf++) {
                bf16x8 pa = *(const bf16x8*)&Ps[qf * 4096 + pcol * 128 + l15 * 8];
                o[qf][0] = __builtin_amdgcn_mfma_f32_16x16x32_bf16(pa, vb[0], o[qf][0], 0, 0, 0);
                o[qf][1] = __builtin_amdgcn_mfma_f32_16x16x32_bf16(pa, vb[1], o[qf][1], 0, 0, 0);
            }
            VMCNT0;        // drain STAGE_V(it+1) before publishing
            __syncthreads();
        }
#pragma unroll
        for (int qf = 0; qf < 8; qf++)
#pragma unroll
            for (int r = 0; r < 4; r++) {
                const int rowl = qf * 16 + lh * 4 + r;
#pragma unroll
                for (int df = 0; df < 2; df++) {
                    const int col = d0 + wave * 32 + df * 16 + l15;
                    aout[((size_t)n * LQc + q0 + rowl) * Dc + col] = o[qf][df][r];
                }
            }
    }
}

// ---------------------------------------------------------------------------
extern "C" void kernel_launch(void* const* d_in, const int* in_sizes, int n_in,
                              void* d_out, int out_size, void* d_ws, size_t ws_size,
                              hipStream_t stream) {
    const float* queries    = (const float*)d_in[0];
    const float* keys       = (const float*)d_in[1];
    const float* values     = (const float*)d_in[2];
    const float* W_q        = (const float*)d_in[3];
    const float* W_k        = (const float*)d_in[4];
    const float* W_v        = (const float*)d_in[5];
    const float* W_o        = (const float*)d_in[6];
    const float* W_len      = (const float*)d_in[7];
    const float* b_len      = (const float*)d_in[8];
    const int*   valid_lens = (const int*)d_in[9];

    char* ws = (char*)d_ws;
    const size_t MB = 1024 * 1024;
    ushort* keysT   = (ushort*)(ws + 64 * MB);        // 32 MB
    ushort* valsT   = (ushort*)(ws + 96 * MB);        // 32 MB
    ushort* qconv   = keysT;                          // aliases keysT+valsT (64 MB)
    ushort* woBf = (ushort*)(ws + 128 * MB);          // 7 x 512 KB consecutive
    ushort* wl   = woBf + 262144;
    ushort* wqT  = wl   + 262144;
    ushort* wkT  = wqT  + 262144;
    ushort* wvT  = wkT  + 262144;
    ushort* Eq   = wvT  + 262144;                     // Eq[d][c]=sum_e Wq[e,d]Wk[e,c]
    ushort* G    = Eq   + 262144;                     // G[e][c]=sum_d Wo[e,d]Wv[d,c]
    ushort* t1k  = G    + 262144;                     // [32][256][512] bf16, 8 MB
    ushort* t1v  = t1k  + 4194304;                    // [32][256][512] bf16, 8 MB
    ushort* k2   = t1v  + 4194304;                    // [32][256][512] bf16, 8 MB
    ushort* v2T  = k2   + 4194304;                    // [32][512][256] bf16, 8 MB

    const float alpha_q = 0.044194173824159216f;      // 1/sqrt(512)
    dim3 blk(256);

    // ---- weight prep: bf16 copies / transposes + folded products --------
    cvt_bf16<<<64, blk, 0, stream>>>(W_o,   woBf, 65536);
    cvt_bf16<<<64, blk, 0, stream>>>(W_len, wl,   65536);
    transpose_cvt<<<dim3(16, 16, 1), blk, 0, stream>>>(W_q, wqT, 512, 512);
    transpose_cvt<<<dim3(16, 16, 1), blk, 0, stream>>>(W_k, wkT, 512, 512);
    transpose_cvt<<<dim3(16, 16, 1), blk, 0, stream>>>(W_v, wvT, 512, 512);
    // Eq[d][c] = sum_e W_q[e,d] * W_k[e,c]
    gemm_bt<1, false, 0><<<dim3(4, 4, 1), blk, 0, stream>>>(
        wqT, wkT, Eq, nullptr, 512, 512, 512, 1.f, 0, 0, 0, 0);
    // G[e][c] = sum_d W_o[e,d] * W_v[d,c]
    gemm_bt<1, false, 0><<<dim3(4, 4, 1), blk, 0, stream>>>(
        woBf, wvT, G, nullptr, 512, 512, 512, 1.f, 0, 0, 0, 0);

    // ---- keys/values: transpose+convert, then length-projection ---------
    transpose_cvt<<<dim3(32, 16, 32), blk, 0, stream>>>(keys,   keysT, LVc, Dc);
    transpose_cvt<<<dim3(32, 16, 32), blk, 0, stream>>>(values, valsT, LVc, Dc);

    // t1k/t1v[b][q][d] = W_len @ {keys,values}_b + b_len   (row-major)
    gemm_bt<1, true, 0><<<dim3(4, 2, 32), blk, 0, stream>>>(
        wl, keysT, t1k, b_len, 256, 512, 1024, 1.f, 0, 524288, 131072, 0);
    gemm_bt<1, true, 0><<<dim3(4, 2, 32), blk, 0, stream>>>(
        wl, valsT, t1v, b_len, 256, 512, 1024, 1.f, 0, 524288, 131072, 0);

    // k2 = t1k @ Eq^T-contraction * alpha   [8192][512]  (q-proj folded away)
    gemm_bt<1, false, 1><<<dim3(256), blk, 0, stream>>>(
        t1k, Eq, k2, nullptr, 8192, 512, 512, alpha_q, 0, 0, 0, 8);
    // v2T[b][e][q] = (t1v @ G^T)^T          (o-proj folded away)
    gemm_bt<2, false, 1><<<dim3(256), blk, 0, stream>>>(
        t1v, G, v2T, nullptr, 8192, 512, 512, 1.f, 0, 0, 0, 8);

    // ---- q: just convert to bf16 (no projection needed) -----------------
    cvt_bf16<<<2048, blk, 0, stream>>>(queries, qconv, 8388608);

    // ---- attention -> final fp32 output directly ------------------------
    attn_mfma<<<dim3(512), blk, 0, stream>>>(qconv, k2, v2T, valid_lens,
                                             (float*)d_out);
}

// Round 14
// 257.907 us; speedup vs baseline: 1.5379x; 1.0771x over previous
//
#include <hip/hip_runtime.h>
#include <math.h>

#define Bc  32
#define Hc  8
#define LQc 256
#define LVc 1024
#define Dc  512

// per-wave drain of outstanding global_load_lds BEFORE a barrier publishes
// the staged LDS to other waves (vmcnt is per-wave; without this the
// legalizer may defer the wait past the barrier -> cross-wave race, R10).
#define VMCNT0 asm volatile("s_waitcnt vmcnt(0)" ::: "memory")

typedef short bf16x8 __attribute__((ext_vector_type(8)));
typedef float f32x4  __attribute__((ext_vector_type(4)));

__device__ __forceinline__ unsigned short f2bf(float x) {   // RNE fp32->bf16
    unsigned u = __builtin_bit_cast(unsigned, x);
    u = (u + 0x7fffu + ((u >> 16) & 1u)) >> 16;
    return (unsigned short)u;
}

__device__ __forceinline__ bf16x8 pack8(float4 a, float4 b) {
    bf16x8 r;
    r[0] = (short)f2bf(a.x); r[1] = (short)f2bf(a.y);
    r[2] = (short)f2bf(a.z); r[3] = (short)f2bf(a.w);
    r[4] = (short)f2bf(b.x); r[5] = (short)f2bf(b.y);
    r[6] = (short)f2bf(b.z); r[7] = (short)f2bf(b.w);
    return r;
}

__device__ __forceinline__ void gload16(const ushort* g, ushort* l) {
    __builtin_amdgcn_global_load_lds(
        (const __attribute__((address_space(1))) unsigned*)g,
        (__attribute__((address_space(3))) unsigned*)l, 16, 0, 0);
}

// ---------------------------------------------------------------------------
// fp32 -> bf16 elementwise convert (vectorized float4 / ushort4)
// ---------------------------------------------------------------------------
__global__ __launch_bounds__(256) void cvt_bf16(const float* __restrict__ in,
                                                ushort* __restrict__ out, int n4) {
    int i = blockIdx.x * 256 + threadIdx.x;
    const int stride = gridDim.x * 256;
    for (; i < n4; i += stride) {
        float4 v = ((const float4*)in)[i];
        ushort4 o;
        o.x = f2bf(v.x); o.y = f2bf(v.y); o.z = f2bf(v.z); o.w = f2bf(v.w);
        ((ushort4*)out)[i] = o;
    }
}

// ---------------------------------------------------------------------------
// fp32 [b][L][D] -> bf16 [b][D][L] transpose+convert, 32x32 LDS tiles
// ---------------------------------------------------------------------------
__global__ __launch_bounds__(256) void transpose_cvt(const float* __restrict__ in,
                                                     ushort* __restrict__ out,
                                                     int L, int D) {
    __shared__ float t[32][33];
    const int b = blockIdx.z;
    const int l0 = blockIdx.x * 32, d0 = blockIdx.y * 32;
    in  += (size_t)b * L * D;
    out += (size_t)b * L * D;
    const int r = threadIdx.x >> 5, c = threadIdx.x & 31;
#pragma unroll
    for (int i = 0; i < 4; i++)
        t[r + 8 * i][c] = in[(size_t)(l0 + r + 8 * i) * D + d0 + c];
    __syncthreads();
#pragma unroll
    for (int i = 0; i < 4; i++)
        out[(size_t)(d0 + r + 8 * i) * L + l0 + c] = f2bf(t[c][r + 8 * i]);
}

// ---------------------------------------------------------------------------
// C[m,n] = alpha * sum_k A[m,k]*B[n,k] (+ bias)         (bf16 in, f32 accum)
// 128x128 tile, BK=32, 4 waves (2x2), 4x4 16x16x32 frags per wave.
// STORE: 0 = f32 row-major, 1 = bf16 row-major (bias[row&255]),
//        2 = bf16 transposed, 256-row batches: out[(m>>8)][n][m&255]
// SWIZ:  1 = 1D grid, XCD-grouped decode
// ---------------------------------------------------------------------------
template <int STORE, bool BIAS, int SWIZ>
__global__ __launch_bounds__(256) void gemm_bt(const ushort* __restrict__ A,
                                               const ushort* __restrict__ B,
                                               void* __restrict__ Cv,
                                               const float* __restrict__ bias,
                                               int M, int N, int K, float alpha,
                                               long sA, long sB, long sC,
                                               int byPerXcd) {
    __shared__ ushort As[128 * 32];
    __shared__ ushort Bs[128 * 32];
    const int z = blockIdx.z;
    A += (size_t)z * sA;
    B += (size_t)z * sB;
    float*  Cf = (float*)Cv  + (size_t)z * sC;
    ushort* Ch = (ushort*)Cv + (size_t)z * sC;

    int bm, bn;
    if constexpr (SWIZ) {
        const int bid = blockIdx.x;
        const int xcd = bid & 7, slot = bid >> 3;
        bm = (xcd * byPerXcd + (slot >> 2)) * 128;
        bn = (slot & 3) * 128;
    } else {
        bm = blockIdx.y * 128;
        bn = blockIdx.x * 128;
    }
    const int tid = threadIdx.x;
    const int wave = tid >> 6, l = tid & 63;
    const int wm = (wave >> 1) * 64, wn = (wave & 1) * 64;
    const int l15 = l & 15, lh = l >> 4;

    f32x4 acc[4][4];
#pragma unroll
    for (int m = 0; m < 4; m++)
#pragma unroll
        for (int n = 0; n < 4; n++) acc[m][n] = (f32x4){0.f, 0.f, 0.f, 0.f};

    const int srow = tid >> 2, scol = (tid & 3) * 8;
    ushort* ldsA = As + (wave * 16) * 32;
    ushort* ldsB = Bs + (wave * 16) * 32;
    const ushort* gA = A + (size_t)(bm + srow) * K + scol;
    const ushort* gB = B + (size_t)(bn + srow) * K + scol;

    for (int k0 = 0; k0 < K; k0 += 32) {
        gload16(gA + k0, ldsA);
        gload16(gA + k0 + (size_t)64 * K, ldsA + 64 * 32);
        gload16(gB + k0, ldsB);
        gload16(gB + k0 + (size_t)64 * K, ldsB + 64 * 32);
        VMCNT0;
        __syncthreads();
        bf16x8 af[4], bfr[4];
#pragma unroll
        for (int m = 0; m < 4; m++)
            af[m] = *(const bf16x8*)&As[(wm + m * 16 + l15) * 32 + lh * 8];
#pragma unroll
        for (int n = 0; n < 4; n++)
            bfr[n] = *(const bf16x8*)&Bs[(wn + n * 16 + l15) * 32 + lh * 8];
#pragma unroll
        for (int m = 0; m < 4; m++)
#pragma unroll
            for (int n = 0; n < 4; n++)
                acc[m][n] = __builtin_amdgcn_mfma_f32_16x16x32_bf16(
                    af[m], bfr[n], acc[m][n], 0, 0, 0);
        __syncthreads();
    }

    if constexpr (STORE == 2) {
#pragma unroll
        for (int m = 0; m < 4; m++) {
            const int row0 = bm + wm + m * 16 + lh * 4;
            const int bb = row0 >> 8, q = row0 & 255;
            float bv[4] = {0.f, 0.f, 0.f, 0.f};
            if constexpr (BIAS) {
#pragma unroll
                for (int r = 0; r < 4; r++) bv[r] = bias[q + r];
            }
#pragma unroll
            for (int n = 0; n < 4; n++) {
                const int col = bn + wn + n * 16 + l15;
                ushort4 o;
                o.x = f2bf(acc[m][n][0] * alpha + bv[0]);
                o.y = f2bf(acc[m][n][1] * alpha + bv[1]);
                o.z = f2bf(acc[m][n][2] * alpha + bv[2]);
                o.w = f2bf(acc[m][n][3] * alpha + bv[3]);
                *(ushort4*)&Ch[(size_t)bb * N * 256 + (size_t)col * 256 + q] = o;
            }
        }
    } else if constexpr (STORE == 1) {
#pragma unroll
        for (int m = 0; m < 4; m++)
#pragma unroll
            for (int r = 0; r < 4; r++) {
                const int row = bm + wm + m * 16 + lh * 4 + r;
                const float bv = BIAS ? bias[row & 255] : 0.f;
#pragma unroll
                for (int n = 0; n < 4; n++) {
                    const int col = bn + wn + n * 16 + l15;
                    Ch[(size_t)row * N + col] = f2bf(acc[m][n][r] * alpha + bv);
                }
            }
    } else {
#pragma unroll
        for (int m = 0; m < 4; m++)
#pragma unroll
            for (int r = 0; r < 4; r++) {
                const int row = bm + wm + m * 16 + lh * 4 + r;
                const float bv = BIAS ? bias[row & 255] : 0.f;
#pragma unroll
                for (int n = 0; n < 4; n++) {
                    const int col = bn + wn + n * 16 + l15;
                    Cf[(size_t)row * N + col] = acc[m][n][r] * alpha + bv;
                }
            }
    }
}

// ---------------------------------------------------------------------------
// Fused attention v7 = v6 + fp32 Q staged directly (cvt fused at fragment
// read). Q staged via gload_lds into chunked fp32 region (layout is linear
// in lane: g*2048 + lane*16, satisfying the wave-uniform-dest rule); bf16
// conversion happens once per fragment (2/wave/iter) via pack8.
// LDS: phase A dbuf 2 x {Qf32 16KB + K 16KB} = 64KB; Ps 64KB aliases it;
// Vs dbuf 2x8KB at [64KB,80KB). vmcnt(0)-before-barrier hardened.
// ---------------------------------------------------------------------------
__global__ __launch_bounds__(256, 2) void attn_mfma(const float* __restrict__ qf,
                                                    const ushort* __restrict__ k2,
                                                    const ushort* __restrict__ v2T,
                                                    const int* __restrict__ vlen,
                                                    float* __restrict__ aout) {
    __shared__ __align__(16) ushort pool[40960];     // 80 KB
    ushort* Ps = pool;                                // chunked P, [0, 32768)

    const int bid = blockIdx.x;
    const int xcd = bid & 7, pos = bid >> 3;      // 64 blocks per XCD
    const int b = xcd * 4 + (pos >> 4);           // 4 batches per XCD
    const int inner = pos & 15;
    const int h = inner >> 1, qh = inner & 1;
    const int n = b * 8 + h;
    const int q0 = qh * 128;

    const int tid = threadIdx.x, wave = tid >> 6, l = tid & 63;
    const int l15 = l & 15, lh = l >> 4;
    const int vl = vlen[b];

    const float*  qbase = qf  + ((size_t)n * LQc + q0) * Dc;
    const ushort* kbase = k2  + (size_t)b * LQc * Dc;
    const ushort* vbase = v2T + (size_t)b * LQc * Dc;

    // ---- phase A: scores 128x256, 2-phase dbuf --------------------------
    f32x4 sacc[2][16];
#pragma unroll
    for (int m = 0; m < 2; m++)
#pragma unroll
        for (int fn = 0; fn < 16; fn++) sacc[m][fn] = (f32x4){0.f, 0.f, 0.f, 0.f};

    auto STAGE_A = [&](int bi, int k0) {
        char* buf = (char*)pool + bi * 32768;     // 32 KB per buffer
        char* qdst = buf;                          // 16KB fp32, chunked
        ushort* kdst = (ushort*)(buf + 16384);     // 16KB bf16, chunked
        // Q fp32: 8 groups of 16 rows; wave stages groups {wave, wave+4},
        // two 1KB halves each (chunks 0-3, 4-7); LDS dest = base + lane*16.
#pragma unroll
        for (int gg = 0; gg < 2; ++gg) {
            const int g = wave + gg * 4;
            const float* srow = qbase + (size_t)(g * 16 + l15) * Dc + k0;
            gload16((const ushort*)(srow + lh * 4),      (ushort*)(qdst + g * 2048));
            gload16((const ushort*)(srow + 16 + lh * 4), (ushort*)(qdst + g * 2048 + 1024));
        }
#pragma unroll
        for (int j = 0; j < 4; j++)
            gload16(kbase + (size_t)((j * 4 + wave) * 16 + l15) * Dc + k0 + lh * 8,
                    kdst + (j * 4 + wave) * 512);
    };

    STAGE_A(0, 0);
    VMCNT0;
    __syncthreads();
    for (int t = 0; t < 16; ++t) {
        if (t < 15) STAGE_A((t + 1) & 1, (t + 1) * 32);
        const char* buf = (const char*)pool + (t & 1) * 32768;
        const ushort* k_ = (const ushort*)(buf + 16384);
        bf16x8 aq[2];
#pragma unroll
        for (int m2 = 0; m2 < 2; ++m2) {
            const int g = 2 * wave + m2;
            const float* fb = (const float*)(buf + g * 2048 + lh * 512 + l15 * 16);
            float4 x0 = *(const float4*)fb;
            float4 x1 = *(const float4*)(fb + 64);    // +256 B
            aq[m2] = pack8(x0, x1);
        }
#pragma unroll
        for (int fn = 0; fn < 16; fn++) {
            bf16x8 bk = *(const bf16x8*)&k_[fn * 512 + lh * 128 + l15 * 8];
            sacc[0][fn] = __builtin_amdgcn_mfma_f32_16x16x32_bf16(aq[0], bk, sacc[0][fn], 0, 0, 0);
            sacc[1][fn] = __builtin_amdgcn_mfma_f32_16x16x32_bf16(aq[1], bk, sacc[1][fn], 0, 0, 0);
        }
        VMCNT0;            // drain STAGE_A(t+1) before publishing via barrier
        __syncthreads();
    }

    // ---- prefetch first V tile (hides under softmax VALU) ---------------
    auto STAGE_V = [&](int bi, int it) {
        const int d0 = (it >> 3) * 128, l0 = (it & 7) * 32;
        ushort* v_ = pool + 32768 + bi * 4096;
        gload16(vbase + (size_t)(d0 + wave * 16 + l15) * LQc + l0 + lh * 8,
                v_ + wave * 512);
        gload16(vbase + (size_t)(d0 + 64 + wave * 16 + l15) * LQc + l0 + lh * 8,
                v_ + (wave + 4) * 512);
    };
    STAGE_V(0, 0);

    // ---- softmax: wave owns rows [32w,32w+32); normalize before write ---
#pragma unroll
    for (int m = 0; m < 2; m++)
#pragma unroll
        for (int r = 0; r < 4; r++) {
            float v[16];
            float rmax = -3.4e38f;
#pragma unroll
            for (int fn = 0; fn < 16; fn++) {
                const int col = fn * 16 + l15;
                float s = sacc[m][fn][r];
                v[fn] = (col < vl) ? s : -1e6f;
                rmax = fmaxf(rmax, v[fn]);
            }
            rmax = fmaxf(rmax, __shfl_xor(rmax, 1));
            rmax = fmaxf(rmax, __shfl_xor(rmax, 2));
            rmax = fmaxf(rmax, __shfl_xor(rmax, 4));
            rmax = fmaxf(rmax, __shfl_xor(rmax, 8));
            float rsum = 0.f;
#pragma unroll
            for (int fn = 0; fn < 16; fn++) {
                v[fn] = __expf(v[fn] - rmax);
                rsum += v[fn];
            }
            rsum += __shfl_xor(rsum, 1);
            rsum += __shfl_xor(rsum, 2);
            rsum += __shfl_xor(rsum, 4);
            rsum += __shfl_xor(rsum, 8);
            const float rinv = 1.0f / rsum;
            // chunked P write: row = wave*32+m*16+lh*4+r, col = fn*16+l15
            const int base = (wave * 2 + m) * 4096 + (lh * 4 + r) * 8 + (l15 & 7);
            const int chi = (l15 >> 3) * 128;
#pragma unroll
            for (int fn = 0; fn < 16; fn++)
                Ps[base + fn * 256 + chi] = f2bf(v[fn] * rinv);
        }
    VMCNT0;                // drain STAGE_V(0,0) before publishing
    __syncthreads();       // Ps visible + V tile 0 loaded

    // ---- phase B: out = P @ v2, 4 d-chunks of 128, 2-phase dbuf ---------
    int it = 0;
    for (int d0 = 0; d0 < Dc; d0 += 128) {
        f32x4 o[8][2];
#pragma unroll
        for (int qf2 = 0; qf2 < 8; qf2++) {
            o[qf2][0] = (f32x4){0.f, 0.f, 0.f, 0.f};
            o[qf2][1] = (f32x4){0.f, 0.f, 0.f, 0.f};
        }
        for (int l0 = 0; l0 < LQc; l0 += 32, ++it) {
            if (it < 31) STAGE_V((it + 1) & 1, it + 1);
            const ushort* v_ = pool + 32768 + (it & 1) * 4096;
            bf16x8 vb[2];
            vb[0] = *(const bf16x8*)&v_[(2 * wave + 0) * 512 + lh * 128 + l15 * 8];
            vb[1] = *(const bf16x8*)&v_[(2 * wave + 1) * 512 + lh * 128 + l15 * 8];
            const int pcol = (l0 >> 3) + lh;     // chunk index of P col
#pragma unroll
            for (int qf2 = 0; qf2 < 8; qf2++) {
                bf16x8 pa = *(const bf16x8*)&Ps[qf2 * 4096 + pcol * 128 + l15 * 8];
                o[qf2][0] = __builtin_amdgcn_mfma_f32_16x16x32_bf16(pa, vb[0], o[qf2][0], 0, 0, 0);
                o[qf2][1] = __builtin_amdgcn_mfma_f32_16x16x32_bf16(pa, vb[1], o[qf2][1], 0, 0, 0);
            }
            VMCNT0;        // drain STAGE_V(it+1) before publishing
            __syncthreads();
        }
#pragma unroll
        for (int qf2 = 0; qf2 < 8; qf2++)
#pragma unroll
            for (int r = 0; r < 4; r++) {
                const int rowl = qf2 * 16 + lh * 4 + r;
#pragma unroll
                for (int df = 0; df < 2; df++) {
                    const int col = d0 + wave * 32 + df * 16 + l15;
                    aout[((size_t)n * LQc + q0 + rowl) * Dc + col] = o[qf2][df][r];
                }
            }
    }
}

// ---------------------------------------------------------------------------
extern "C" void kernel_launch(void* const* d_in, const int* in_sizes, int n_in,
                              void* d_out, int out_size, void* d_ws, size_t ws_size,
                              hipStream_t stream) {
    const float* queries    = (const float*)d_in[0];
    const float* keys       = (const float*)d_in[1];
    const float* values     = (const float*)d_in[2];
    const float* W_q        = (const float*)d_in[3];
    const float* W_k        = (const float*)d_in[4];
    const float* W_v        = (const float*)d_in[5];
    const float* W_o        = (const float*)d_in[6];
    const float* W_len      = (const float*)d_in[7];
    const float* b_len      = (const float*)d_in[8];
    const int*   valid_lens = (const int*)d_in[9];

    char* ws = (char*)d_ws;
    const size_t MB = 1024 * 1024;
    ushort* keysT   = (ushort*)(ws + 64 * MB);        // 32 MB
    ushort* valsT   = (ushort*)(ws + 96 * MB);        // 32 MB
    ushort* woBf = (ushort*)(ws + 128 * MB);          // 7 x 512 KB consecutive
    ushort* wl   = woBf + 262144;
    ushort* wqT  = wl   + 262144;
    ushort* wkT  = wqT  + 262144;
    ushort* wvT  = wkT  + 262144;
    ushort* Eq   = wvT  + 262144;                     // Eq[d][c]=sum_e Wq[e,d]Wk[e,c]
    ushort* G    = Eq   + 262144;                     // G[e][c]=sum_d Wo[e,d]Wv[d,c]
    ushort* t1k  = G    + 262144;                     // [32][256][512] bf16, 8 MB
    ushort* t1v  = t1k  + 4194304;                    // [32][256][512] bf16, 8 MB
    ushort* k2   = t1v  + 4194304;                    // [32][256][512] bf16, 8 MB
    ushort* v2T  = k2   + 4194304;                    // [32][512][256] bf16, 8 MB

    const float alpha_q = 0.044194173824159216f;      // 1/sqrt(512)
    dim3 blk(256);

    // ---- weight prep: bf16 copies / transposes + folded products --------
    cvt_bf16<<<64, blk, 0, stream>>>(W_o,   woBf, 65536);
    cvt_bf16<<<64, blk, 0, stream>>>(W_len, wl,   65536);
    transpose_cvt<<<dim3(16, 16, 1), blk, 0, stream>>>(W_q, wqT, 512, 512);
    transpose_cvt<<<dim3(16, 16, 1), blk, 0, stream>>>(W_k, wkT, 512, 512);
    transpose_cvt<<<dim3(16, 16, 1), blk, 0, stream>>>(W_v, wvT, 512, 512);
    // Eq[d][c] = sum_e W_q[e,d] * W_k[e,c]
    gemm_bt<1, false, 0><<<dim3(4, 4, 1), blk, 0, stream>>>(
        wqT, wkT, Eq, nullptr, 512, 512, 512, 1.f, 0, 0, 0, 0);
    // G[e][c] = sum_d W_o[e,d] * W_v[d,c]
    gemm_bt<1, false, 0><<<dim3(4, 4, 1), blk, 0, stream>>>(
        woBf, wvT, G, nullptr, 512, 512, 512, 1.f, 0, 0, 0, 0);

    // ---- keys/values: transpose+convert, then length-projection ---------
    transpose_cvt<<<dim3(32, 16, 32), blk, 0, stream>>>(keys,   keysT, LVc, Dc);
    transpose_cvt<<<dim3(32, 16, 32), blk, 0, stream>>>(values, valsT, LVc, Dc);

    // t1k/t1v[b][q][d] = W_len @ {keys,values}_b + b_len   (row-major)
    gemm_bt<1, true, 0><<<dim3(4, 2, 32), blk, 0, stream>>>(
        wl, keysT, t1k, b_len, 256, 512, 1024, 1.f, 0, 524288, 131072, 0);
    gemm_bt<1, true, 0><<<dim3(4, 2, 32), blk, 0, stream>>>(
        wl, valsT, t1v, b_len, 256, 512, 1024, 1.f, 0, 524288, 131072, 0);

    // k2 = t1k @ Eq-contraction * alpha   [8192][512]  (q-proj folded away)
    gemm_bt<1, false, 1><<<dim3(256), blk, 0, stream>>>(
        t1k, Eq, k2, nullptr, 8192, 512, 512, alpha_q, 0, 0, 0, 8);
    // v2T[b][e][q] = (t1v @ G^T)^T          (o-proj folded away)
    gemm_bt<2, false, 1><<<dim3(256), blk, 0, stream>>>(
        t1v, G, v2T, nullptr, 8192, 512, 512, 1.f, 0, 0, 0, 8);

    // ---- attention (raw fp32 queries, cvt fused) -> fp32 d_out ----------
    attn_mfma<<<dim3(512), blk, 0, stream>>>(queries, k2, v2T, valid_lens,
                                             (float*)d_out);
}

// Round 15
// 219.380 us; speedup vs baseline: 1.8080x; 1.1756x over previous
//
#include <hip/hip_runtime.h>
#include <math.h>

#define Bc  32
#define Hc  8
#define LQc 256
#define LVc 1024
#define Dc  512

// per-wave drain of outstanding global_load_lds BEFORE a barrier publishes
// the staged LDS to other waves (vmcnt is per-wave; without this the
// legalizer may defer the wait past the barrier -> cross-wave race, R10).
#define VMCNT0 asm volatile("s_waitcnt vmcnt(0)" ::: "memory")

typedef short bf16x8 __attribute__((ext_vector_type(8)));
typedef float f32x4  __attribute__((ext_vector_type(4)));

__device__ __forceinline__ unsigned short f2bf(float x) {   // RNE fp32->bf16
    unsigned u = __builtin_bit_cast(unsigned, x);
    u = (u + 0x7fffu + ((u >> 16) & 1u)) >> 16;
    return (unsigned short)u;
}

__device__ __forceinline__ bf16x8 pack8(float4 a, float4 b) {
    bf16x8 r;
    r[0] = (short)f2bf(a.x); r[1] = (short)f2bf(a.y);
    r[2] = (short)f2bf(a.z); r[3] = (short)f2bf(a.w);
    r[4] = (short)f2bf(b.x); r[5] = (short)f2bf(b.y);
    r[6] = (short)f2bf(b.z); r[7] = (short)f2bf(b.w);
    return r;
}

__device__ __forceinline__ void gload16(const ushort* g, ushort* l) {
    __builtin_amdgcn_global_load_lds(
        (const __attribute__((address_space(1))) unsigned*)g,
        (__attribute__((address_space(3))) unsigned*)l, 16, 0, 0);
}

// ---------------------------------------------------------------------------
// All weight prep in ONE launch. grid (16,16,5), 256 thr.
// z=0,1,2: transpose+cvt W_q,W_k,W_v (512x512);  z=3,4: cvt W_o, W_len.
// ---------------------------------------------------------------------------
__global__ __launch_bounds__(256) void prep_w(const float* __restrict__ Wq,
                                              const float* __restrict__ Wk,
                                              const float* __restrict__ Wv,
                                              const float* __restrict__ Wo,
                                              const float* __restrict__ Wl,
                                              ushort* __restrict__ wqT,
                                              ushort* __restrict__ wkT,
                                              ushort* __restrict__ wvT,
                                              ushort* __restrict__ woBf,
                                              ushort* __restrict__ wlBf) {
    const int z = blockIdx.z;
    if (z < 3) {
        __shared__ float t[32][33];
        const float* in = (z == 0) ? Wq : (z == 1) ? Wk : Wv;
        ushort* out = (z == 0) ? wqT : (z == 1) ? wkT : wvT;
        const int l0 = blockIdx.x * 32, d0 = blockIdx.y * 32;
        const int r = threadIdx.x >> 5, c = threadIdx.x & 31;
#pragma unroll
        for (int i = 0; i < 4; i++)
            t[r + 8 * i][c] = in[(size_t)(l0 + r + 8 * i) * 512 + d0 + c];
        __syncthreads();
#pragma unroll
        for (int i = 0; i < 4; i++)
            out[(size_t)(d0 + r + 8 * i) * 512 + l0 + c] = f2bf(t[c][r + 8 * i]);
    } else {
        const float* in = (z == 3) ? Wo : Wl;
        ushort* out = (z == 3) ? woBf : wlBf;
        const int i = (blockIdx.y * 16 + blockIdx.x) * 256 + threadIdx.x;  // 65536 float4s
        float4 v = ((const float4*)in)[i];
        ushort4 o;
        o.x = f2bf(v.x); o.y = f2bf(v.y); o.z = f2bf(v.z); o.w = f2bf(v.w);
        ((ushort4*)out)[i] = o;
    }
}

// ---------------------------------------------------------------------------
// keys AND values -> bf16 [b][D][L] transpose, one launch. grid (32,16,64).
// z in [0,32): keys batch z; z in [32,64): values batch z-32.
// outK is keysT; valsT = outK + 32*LVc*Dc (contiguous).
// ---------------------------------------------------------------------------
__global__ __launch_bounds__(256) void transpose_kv(const float* __restrict__ keys,
                                                    const float* __restrict__ vals,
                                                    ushort* __restrict__ outK) {
    __shared__ float t[32][33];
    const int z = blockIdx.z;
    const float* in = ((z < 32) ? keys : vals) + (size_t)(z & 31) * LVc * Dc;
    ushort* out = outK + (size_t)z * LVc * Dc;
    const int l0 = blockIdx.x * 32, d0 = blockIdx.y * 32;
    const int r = threadIdx.x >> 5, c = threadIdx.x & 31;
#pragma unroll
    for (int i = 0; i < 4; i++)
        t[r + 8 * i][c] = in[(size_t)(l0 + r + 8 * i) * Dc + d0 + c];
    __syncthreads();
#pragma unroll
    for (int i = 0; i < 4; i++)
        out[(size_t)(d0 + r + 8 * i) * LVc + l0 + c] = f2bf(t[c][r + 8 * i]);
}

// ---------------------------------------------------------------------------
// C[m,n] = alpha * sum_k A[m,k]*B[n,k] (+ bias)         (bf16 in, f32 accum)
// 128x128 tile, BK=32, 4 waves (2x2), 4x4 16x16x32 frags per wave.
// STORE: 0 = f32 row-major, 1 = bf16 row-major (bias[row&255]),
//        2 = bf16 transposed, 256-row batches: out[(m>>8)][n][m&255]
// SWIZ:  1 = 1D grid, XCD-grouped decode
// ---------------------------------------------------------------------------
template <int STORE, bool BIAS, int SWIZ>
__global__ __launch_bounds__(256) void gemm_bt(const ushort* __restrict__ A,
                                               const ushort* __restrict__ B,
                                               void* __restrict__ Cv,
                                               const float* __restrict__ bias,
                                               int M, int N, int K, float alpha,
                                               long sA, long sB, long sC,
                                               int byPerXcd) {
    __shared__ ushort As[128 * 32];
    __shared__ ushort Bs[128 * 32];
    const int z = blockIdx.z;
    A += (size_t)z * sA;
    B += (size_t)z * sB;
    float*  Cf = (float*)Cv  + (size_t)z * sC;
    ushort* Ch = (ushort*)Cv + (size_t)z * sC;

    int bm, bn;
    if constexpr (SWIZ) {
        const int bid = blockIdx.x;
        const int xcd = bid & 7, slot = bid >> 3;
        bm = (xcd * byPerXcd + (slot >> 2)) * 128;
        bn = (slot & 3) * 128;
    } else {
        bm = blockIdx.y * 128;
        bn = blockIdx.x * 128;
    }
    const int tid = threadIdx.x;
    const int wave = tid >> 6, l = tid & 63;
    const int wm = (wave >> 1) * 64, wn = (wave & 1) * 64;
    const int l15 = l & 15, lh = l >> 4;

    f32x4 acc[4][4];
#pragma unroll
    for (int m = 0; m < 4; m++)
#pragma unroll
        for (int n = 0; n < 4; n++) acc[m][n] = (f32x4){0.f, 0.f, 0.f, 0.f};

    const int srow = tid >> 2, scol = (tid & 3) * 8;
    ushort* ldsA = As + (wave * 16) * 32;
    ushort* ldsB = Bs + (wave * 16) * 32;
    const ushort* gA = A + (size_t)(bm + srow) * K + scol;
    const ushort* gB = B + (size_t)(bn + srow) * K + scol;

    for (int k0 = 0; k0 < K; k0 += 32) {
        gload16(gA + k0, ldsA);
        gload16(gA + k0 + (size_t)64 * K, ldsA + 64 * 32);
        gload16(gB + k0, ldsB);
        gload16(gB + k0 + (size_t)64 * K, ldsB + 64 * 32);
        VMCNT0;
        __syncthreads();
        bf16x8 af[4], bfr[4];
#pragma unroll
        for (int m = 0; m < 4; m++)
            af[m] = *(const bf16x8*)&As[(wm + m * 16 + l15) * 32 + lh * 8];
#pragma unroll
        for (int n = 0; n < 4; n++)
            bfr[n] = *(const bf16x8*)&Bs[(wn + n * 16 + l15) * 32 + lh * 8];
#pragma unroll
        for (int m = 0; m < 4; m++)
#pragma unroll
            for (int n = 0; n < 4; n++)
                acc[m][n] = __builtin_amdgcn_mfma_f32_16x16x32_bf16(
                    af[m], bfr[n], acc[m][n], 0, 0, 0);
        __syncthreads();
    }

    if constexpr (STORE == 2) {
#pragma unroll
        for (int m = 0; m < 4; m++) {
            const int row0 = bm + wm + m * 16 + lh * 4;
            const int bb = row0 >> 8, q = row0 & 255;
            float bv[4] = {0.f, 0.f, 0.f, 0.f};
            if constexpr (BIAS) {
#pragma unroll
                for (int r = 0; r < 4; r++) bv[r] = bias[q + r];
            }
#pragma unroll
            for (int n = 0; n < 4; n++) {
                const int col = bn + wn + n * 16 + l15;
                ushort4 o;
                o.x = f2bf(acc[m][n][0] * alpha + bv[0]);
                o.y = f2bf(acc[m][n][1] * alpha + bv[1]);
                o.z = f2bf(acc[m][n][2] * alpha + bv[2]);
                o.w = f2bf(acc[m][n][3] * alpha + bv[3]);
                *(ushort4*)&Ch[(size_t)bb * N * 256 + (size_t)col * 256 + q] = o;
            }
        }
    } else if constexpr (STORE == 1) {
#pragma unroll
        for (int m = 0; m < 4; m++)
#pragma unroll
            for (int r = 0; r < 4; r++) {
                const int row = bm + wm + m * 16 + lh * 4 + r;
                const float bv = BIAS ? bias[row & 255] : 0.f;
#pragma unroll
                for (int n = 0; n < 4; n++) {
                    const int col = bn + wn + n * 16 + l15;
                    Ch[(size_t)row * N + col] = f2bf(acc[m][n][r] * alpha + bv);
                }
            }
    } else {
#pragma unroll
        for (int m = 0; m < 4; m++)
#pragma unroll
            for (int r = 0; r < 4; r++) {
                const int row = bm + wm + m * 16 + lh * 4 + r;
                const float bv = BIAS ? bias[row & 255] : 0.f;
#pragma unroll
                for (int n = 0; n < 4; n++) {
                    const int col = bn + wn + n * 16 + l15;
                    Cf[(size_t)row * N + col] = acc[m][n][r] * alpha + bv;
                }
            }
    }
}

// ---------------------------------------------------------------------------
// Fused attention v8 = v7 with Q DIRECT-TO-REGISTER (no Q LDS staging).
// Q has zero reuse across phase-A iterations, so each lane loads its own
// fragment bytes (2 x float4 per frag) from global and packs to bf16.
// Phase A stages only K (dbuf 2x16KB, chunked, aliasing Ps); Vs unchanged.
// vmcnt(0)-before-barrier hardened. Output fp32 direct to d_out.
// ---------------------------------------------------------------------------
__global__ __launch_bounds__(256, 2) void attn_mfma(const float* __restrict__ qf,
                                                    const ushort* __restrict__ k2,
                                                    const ushort* __restrict__ v2T,
                                                    const int* __restrict__ vlen,
                                                    float* __restrict__ aout) {
    __shared__ __align__(16) ushort pool[40960];     // 80 KB
    ushort* Ps = pool;                                // chunked P, [0, 32768)

    const int bid = blockIdx.x;
    const int xcd = bid & 7, pos = bid >> 3;      // 64 blocks per XCD
    const int b = xcd * 4 + (pos >> 4);           // 4 batches per XCD
    const int inner = pos & 15;
    const int h = inner >> 1, qh = inner & 1;
    const int n = b * 8 + h;
    const int q0 = qh * 128;

    const int tid = threadIdx.x, wave = tid >> 6, l = tid & 63;
    const int l15 = l & 15, lh = l >> 4;
    const int vl = vlen[b];

    const float*  qbase = qf  + ((size_t)n * LQc + q0) * Dc;
    const ushort* kbase = k2  + (size_t)b * LQc * Dc;
    const ushort* vbase = v2T + (size_t)b * LQc * Dc;

    // ---- phase A: scores 128x256; K dbuf in LDS, Q direct to regs -------
    f32x4 sacc[2][16];
#pragma unroll
    for (int m = 0; m < 2; m++)
#pragma unroll
        for (int fn = 0; fn < 16; fn++) sacc[m][fn] = (f32x4){0.f, 0.f, 0.f, 0.f};

    auto STAGE_K = [&](int bi, int k0) {
        ushort* k_ = pool + bi * 8192;            // 16 KB per buffer
#pragma unroll
        for (int j = 0; j < 4; j++)
            gload16(kbase + (size_t)((j * 4 + wave) * 16 + l15) * Dc + k0 + lh * 8,
                    k_ + (j * 4 + wave) * 512);
    };

    STAGE_K(0, 0);
    VMCNT0;
    __syncthreads();
    for (int t = 0; t < 16; ++t) {
        const int k0 = t * 32;
        if (t < 15) STAGE_K((t + 1) & 1, k0 + 32);
        // Q fragments straight from global (read-once data)
        bf16x8 aq[2];
#pragma unroll
        for (int m2 = 0; m2 < 2; ++m2) {
            const float* fb = qbase + (size_t)(wave * 32 + m2 * 16 + l15) * Dc + k0 + lh * 8;
            float4 x0 = *(const float4*)fb;
            float4 x1 = *(const float4*)(fb + 4);
            aq[m2] = pack8(x0, x1);
        }
        const ushort* k_ = pool + (t & 1) * 8192;
#pragma unroll
        for (int fn = 0; fn < 16; fn++) {
            bf16x8 bk = *(const bf16x8*)&k_[fn * 512 + lh * 128 + l15 * 8];
            sacc[0][fn] = __builtin_amdgcn_mfma_f32_16x16x32_bf16(aq[0], bk, sacc[0][fn], 0, 0, 0);
            sacc[1][fn] = __builtin_amdgcn_mfma_f32_16x16x32_bf16(aq[1], bk, sacc[1][fn], 0, 0, 0);
        }
        VMCNT0;            // drain STAGE_K(t+1) before publishing via barrier
        __syncthreads();
    }

    // ---- prefetch first V tile (hides under softmax VALU) ---------------
    auto STAGE_V = [&](int bi, int it) {
        const int d0 = (it >> 3) * 128, l0 = (it & 7) * 32;
        ushort* v_ = pool + 32768 + bi * 4096;
        gload16(vbase + (size_t)(d0 + wave * 16 + l15) * LQc + l0 + lh * 8,
                v_ + wave * 512);
        gload16(vbase + (size_t)(d0 + 64 + wave * 16 + l15) * LQc + l0 + lh * 8,
                v_ + (wave + 4) * 512);
    };
    STAGE_V(0, 0);

    // ---- softmax: wave owns rows [32w,32w+32); normalize before write ---
#pragma unroll
    for (int m = 0; m < 2; m++)
#pragma unroll
        for (int r = 0; r < 4; r++) {
            float v[16];
            float rmax = -3.4e38f;
#pragma unroll
            for (int fn = 0; fn < 16; fn++) {
                const int col = fn * 16 + l15;
                float s = sacc[m][fn][r];
                v[fn] = (col < vl) ? s : -1e6f;
                rmax = fmaxf(rmax, v[fn]);
            }
            rmax = fmaxf(rmax, __shfl_xor(rmax, 1));
            rmax = fmaxf(rmax, __shfl_xor(rmax, 2));
            rmax = fmaxf(rmax, __shfl_xor(rmax, 4));
            rmax = fmaxf(rmax, __shfl_xor(rmax, 8));
            float rsum = 0.f;
#pragma unroll
            for (int fn = 0; fn < 16; fn++) {
                v[fn] = __expf(v[fn] - rmax);
                rsum += v[fn];
            }
            rsum += __shfl_xor(rsum, 1);
            rsum += __shfl_xor(rsum, 2);
            rsum += __shfl_xor(rsum, 4);
            rsum += __shfl_xor(rsum, 8);
            const float rinv = 1.0f / rsum;
            // chunked P write: row = wave*32+m*16+lh*4+r, col = fn*16+l15
            const int base = (wave * 2 + m) * 4096 + (lh * 4 + r) * 8 + (l15 & 7);
            const int chi = (l15 >> 3) * 128;
#pragma unroll
            for (int fn = 0; fn < 16; fn++)
                Ps[base + fn * 256 + chi] = f2bf(v[fn] * rinv);
        }
    VMCNT0;                // drain STAGE_V(0,0) before publishing
    __syncthreads();       // Ps visible + V tile 0 loaded

    // ---- phase B: out = P @ v2, 4 d-chunks of 128, 2-phase dbuf ---------
    int it = 0;
    for (int d0 = 0; d0 < Dc; d0 += 128) {
        f32x4 o[8][2];
#pragma unroll
        for (int qf2 = 0; qf2 < 8; qf2++) {
            o[qf2][0] = (f32x4){0.f, 0.f, 0.f, 0.f};
            o[qf2][1] = (f32x4){0.f, 0.f, 0.f, 0.f};
        }
        for (int l0 = 0; l0 < LQc; l0 += 32, ++it) {
            if (it < 31) STAGE_V((it + 1) & 1, it + 1);
            const ushort* v_ = pool + 32768 + (it & 1) * 4096;
            bf16x8 vb[2];
            vb[0] = *(const bf16x8*)&v_[(2 * wave + 0) * 512 + lh * 128 + l15 * 8];
            vb[1] = *(const bf16x8*)&v_[(2 * wave + 1) * 512 + lh * 128 + l15 * 8];
            const int pcol = (l0 >> 3) + lh;     // chunk index of P col
#pragma unroll
            for (int qf2 = 0; qf2 < 8; qf2++) {
                bf16x8 pa = *(const bf16x8*)&Ps[qf2 * 4096 + pcol * 128 + l15 * 8];
                o[qf2][0] = __builtin_amdgcn_mfma_f32_16x16x32_bf16(pa, vb[0], o[qf2][0], 0, 0, 0);
                o[qf2][1] = __builtin_amdgcn_mfma_f32_16x16x32_bf16(pa, vb[1], o[qf2][1], 0, 0, 0);
            }
            VMCNT0;        // drain STAGE_V(it+1) before publishing
            __syncthreads();
        }
#pragma unroll
        for (int qf2 = 0; qf2 < 8; qf2++)
#pragma unroll
            for (int r = 0; r < 4; r++) {
                const int rowl = qf2 * 16 + lh * 4 + r;
#pragma unroll
                for (int df = 0; df < 2; df++) {
                    const int col = d0 + wave * 32 + df * 16 + l15;
                    aout[((size_t)n * LQc + q0 + rowl) * Dc + col] = o[qf2][df][r];
                }
            }
    }
}

// ---------------------------------------------------------------------------
extern "C" void kernel_launch(void* const* d_in, const int* in_sizes, int n_in,
                              void* d_out, int out_size, void* d_ws, size_t ws_size,
                              hipStream_t stream) {
    const float* queries    = (const float*)d_in[0];
    const float* keys       = (const float*)d_in[1];
    const float* values     = (const float*)d_in[2];
    const float* W_q        = (const float*)d_in[3];
    const float* W_k        = (const float*)d_in[4];
    const float* W_v        = (const float*)d_in[5];
    const float* W_o        = (const float*)d_in[6];
    const float* W_len      = (const float*)d_in[7];
    const float* b_len      = (const float*)d_in[8];
    const int*   valid_lens = (const int*)d_in[9];

    char* ws = (char*)d_ws;
    const size_t MB = 1024 * 1024;
    ushort* keysT   = (ushort*)(ws + 64 * MB);        // 32 MB (+ valsT 32 MB contig)
    ushort* woBf = (ushort*)(ws + 128 * MB);          // 7 x 512 KB consecutive
    ushort* wl   = woBf + 262144;
    ushort* wqT  = wl   + 262144;
    ushort* wkT  = wqT  + 262144;
    ushort* wvT  = wkT  + 262144;
    ushort* Eq   = wvT  + 262144;                     // Eq[d][c]=sum_e Wq[e,d]Wk[e,c]
    ushort* G    = Eq   + 262144;                     // G[e][c]=sum_d Wo[e,d]Wv[d,c]
    ushort* t1k  = G    + 262144;                     // [32][256][512] bf16, 8 MB (+ t1v contig)
    ushort* t1v  = t1k  + 4194304;
    ushort* k2   = t1v  + 4194304;                    // [32][256][512] bf16, 8 MB
    ushort* v2T  = k2   + 4194304;                    // [32][512][256] bf16, 8 MB

    const float alpha_q = 0.044194173824159216f;      // 1/sqrt(512)
    dim3 blk(256);

    // ---- all weight prep in one launch ----------------------------------
    prep_w<<<dim3(16, 16, 5), blk, 0, stream>>>(W_q, W_k, W_v, W_o, W_len,
                                                wqT, wkT, wvT, woBf, wl);
    // folded products
    gemm_bt<1, false, 0><<<dim3(4, 4, 1), blk, 0, stream>>>(
        wqT, wkT, Eq, nullptr, 512, 512, 512, 1.f, 0, 0, 0, 0);
    gemm_bt<1, false, 0><<<dim3(4, 4, 1), blk, 0, stream>>>(
        woBf, wvT, G, nullptr, 512, 512, 512, 1.f, 0, 0, 0, 0);

    // ---- keys+values transpose (one launch) ------------------------------
    transpose_kv<<<dim3(32, 16, 64), blk, 0, stream>>>(keys, values, keysT);

    // ---- both length-projections in one launch (B, C regions contiguous) -
    gemm_bt<1, true, 0><<<dim3(4, 2, 64), blk, 0, stream>>>(
        wl, keysT, t1k, b_len, 256, 512, 1024, 1.f, 0, 524288, 131072, 0);

    // k2 = t1k @ Eq-contraction * alpha   (q-proj folded away)
    gemm_bt<1, false, 1><<<dim3(256), blk, 0, stream>>>(
        t1k, Eq, k2, nullptr, 8192, 512, 512, alpha_q, 0, 0, 0, 8);
    // v2T[b][e][q] = (t1v @ G^T)^T          (o-proj folded away)
    gemm_bt<2, false, 1><<<dim3(256), blk, 0, stream>>>(
        t1v, G, v2T, nullptr, 8192, 512, 512, 1.f, 0, 0, 0, 8);

    // ---- attention (raw fp32 queries, reg-Q) -> fp32 d_out ---------------
    attn_mfma<<<dim3(512), blk, 0, stream>>>(queries, k2, v2T, valid_lens,
                                             (float*)d_out);
}